// Round 1
// baseline (1424.126 us; speedup 1.0000x reference)
//
#include <hip/hip_runtime.h>
#include <cmath>

#define B 32
#define S 11
#define R 16
#define D 64
#define C 512
#define N 256   // R*R
#define LN_EPS 1e-3f

__device__ __forceinline__ float grid_coord(int i) {
    return -1.0f + (2.0f / 15.0f) * (float)i;
}

// ---------------- K0: positional embedding pos[n, c] (once) ----------------
__global__ __launch_bounds__(128) void pos_kernel(
    const float* __restrict__ es_w1, const float* __restrict__ es_b1,
    const float* __restrict__ es_w2, const float* __restrict__ es_b2,
    float* __restrict__ pos) {
    int n = blockIdx.x;       // 0..255
    int j = threadIdx.x;      // 0..127
    float g0 = grid_coord(n >> 4), g1 = grid_coord(n & 15);
    __shared__ float h[128];
    float hj = es_b1[j] + g0 * es_w1[j] + g1 * es_w1[128 + j];
    h[j] = fmaxf(hj, 0.0f);
    __syncthreads();
    for (int c0 = 0; c0 < C; c0 += 128) {
        int c = c0 + j;
        float acc = es_b2[c];
        #pragma unroll 16
        for (int jj = 0; jj < 128; ++jj) acc += h[jj] * es_w2[jj * C + c];
        pos[n * C + c] = acc;
    }
}

// ---------------- K_init: slots = slots_mu broadcast, s_p/s_s init ----------
__global__ void init_kernel(
    const float* __restrict__ slots_mu, const float* __restrict__ s_p0,
    const float* __restrict__ s_s0,
    float* __restrict__ slots, float* __restrict__ s_p, float* __restrict__ s_s) {
    int idx = blockIdx.x * blockDim.x + threadIdx.x;
    if (idx < B * S * D) slots[idx] = slots_mu[idx % (S * D)];
    if (idx < B * S * 2) { s_p[idx] = s_p0[idx]; s_s[idx] = s_s0[idx]; }
}

// ---------------- K1: inputs_k / inputs_v projection (once) -----------------
// x = inputs + pos;  ik = x @ pk_w + pk_b;  iv = x @ pv_w + pv_b
__global__ __launch_bounds__(256) void projkv_kernel(
    const float* __restrict__ inputs, const float* __restrict__ pos,
    const float* __restrict__ pk_w, const float* __restrict__ pk_b,
    const float* __restrict__ pv_w, const float* __restrict__ pv_b,
    float* __restrict__ ik, float* __restrict__ iv) {
    int b = blockIdx.x >> 3;      // 32 batches
    int tile = blockIdx.x & 7;    // 8 tiles of 32 rows
    int n0 = tile * 32;
    int tid = threadIdx.x;
    int d = tid & 63;
    int wv = tid >> 6;            // wave id 0..3 -> rows wv*8 .. wv*8+7
    __shared__ float xs[32][128];
    float accK[8], accV[8];
    #pragma unroll
    for (int r = 0; r < 8; ++r) { accK[r] = pk_b[d]; accV[r] = pv_b[d]; }
    for (int cc = 0; cc < C; cc += 128) {
        __syncthreads();
        for (int e = tid; e < 32 * 128; e += 256) {
            int row = e >> 7, col = e & 127;
            int n = n0 + row;
            xs[row][col] = inputs[(b * N + n) * C + cc + col] + pos[n * C + cc + col];
        }
        __syncthreads();
        for (int c = 0; c < 128; ++c) {
            float wk = pk_w[(cc + c) * D + d];
            float wvv = pv_w[(cc + c) * D + d];
            #pragma unroll
            for (int r = 0; r < 8; ++r) {
                float x = xs[wv * 8 + r][c];
                accK[r] += x * wk;
                accV[r] += x * wvv;
            }
        }
    }
    #pragma unroll
    for (int r = 0; r < 8; ++r) {
        int n = n0 + wv * 8 + r;
        ik[(b * N + n) * D + d] = accK[r];
        iv[(b * N + n) * D + d] = accV[r];
    }
}

// ---------------- K2: q = (LN(slots) @ pq_w + pq_b) * D^-0.5 ----------------
__global__ __launch_bounds__(64) void q_kernel(
    const float* __restrict__ slots,
    const float* __restrict__ ns_g, const float* __restrict__ ns_b,
    const float* __restrict__ pq_w, const float* __restrict__ pq_b,
    float* __restrict__ q) {
    int bs = blockIdx.x;   // 0..351
    int d = threadIdx.x;   // 0..63
    float x = slots[bs * D + d];
    float sum = x;
    #pragma unroll
    for (int off = 32; off > 0; off >>= 1) sum += __shfl_xor(sum, off);
    float m = sum * (1.0f / 64.0f);
    float dx = x - m;
    float vs = dx * dx;
    #pragma unroll
    for (int off = 32; off > 0; off >>= 1) vs += __shfl_xor(vs, off);
    float var = vs * (1.0f / 64.0f);
    float xln = dx * rsqrtf(var + LN_EPS) * ns_g[d] + ns_b[d];
    __shared__ float lds[64];
    lds[d] = xln;
    __syncthreads();
    float acc = pq_b[d];
    #pragma unroll 8
    for (int i = 0; i < 64; ++i) acc += lds[i] * pq_w[i * D + d];
    q[bs * D + d] = acc * 0.125f;   // D^-0.5 = 1/8
}

// ---------------- K3: the big one: pe, k-MLP->logit, v-MLP->v_buf -----------
__global__ __launch_bounds__(128) void kv_kernel(
    const float* __restrict__ ik, const float* __restrict__ iv,
    const float* __restrict__ s_p, const float* __restrict__ s_s,
    const float* __restrict__ er_w, const float* __restrict__ er_b,
    const float* __restrict__ mi_w1, const float* __restrict__ mi_b1,
    const float* __restrict__ mi_w2, const float* __restrict__ mi_b2,
    const float* __restrict__ q,
    float* __restrict__ v_buf, float* __restrict__ logits) {
    int blk = blockIdx.x;       // B*S*2 = 704
    int half = blk & 1;
    int bs = blk >> 1;          // 0..351
    int b = bs / S, s = bs % S;
    int n = half * 128 + threadIdx.x;
    float p0 = s_p[bs * 2 + 0], p1 = s_p[bs * 2 + 1];
    float ss0 = s_s[bs * 2 + 0], ss1 = s_s[bs * 2 + 1];
    float g0 = grid_coord(n >> 4), g1 = grid_coord(n & 15);
    float r0 = (g0 - p0) / ss0, r1 = (g1 - p1) / ss1;

    const float4* ik4 = (const float4*)(ik + (b * N + n) * D);
    const float4* iv4 = (const float4*)(iv + (b * N + n) * D);

    float in_[D], acc[D];

    // ---- k path (k only feeds the logit dot with q) ----
    #pragma unroll
    for (int i4 = 0; i4 < 16; ++i4) {
        float4 t = ik4[i4];
        int i = i4 * 4;
        in_[i + 0] = t.x + r0 * er_w[i + 0] + r1 * er_w[D + i + 0] + er_b[i + 0];
        in_[i + 1] = t.y + r0 * er_w[i + 1] + r1 * er_w[D + i + 1] + er_b[i + 1];
        in_[i + 2] = t.z + r0 * er_w[i + 2] + r1 * er_w[D + i + 2] + er_b[i + 2];
        in_[i + 3] = t.w + r0 * er_w[i + 3] + r1 * er_w[D + i + 3] + er_b[i + 3];
    }
    #pragma unroll
    for (int dd = 0; dd < D; ++dd) acc[dd] = mi_b2[dd];
    #pragma unroll 2
    for (int j = 0; j < 128; ++j) {
        float h = mi_b1[j];
        #pragma unroll
        for (int i = 0; i < D; ++i) h += in_[i] * mi_w1[i * 128 + j];
        h = fmaxf(h, 0.0f);
        #pragma unroll
        for (int dd = 0; dd < D; ++dd) acc[dd] += h * mi_w2[j * D + dd];
    }
    float lg = 0.0f;
    #pragma unroll
    for (int dd = 0; dd < D; ++dd) lg += acc[dd] * q[bs * D + dd];
    logits[(b * N + n) * S + s] = lg;

    // ---- v path ----
    #pragma unroll
    for (int i4 = 0; i4 < 16; ++i4) {
        float4 t = iv4[i4];
        int i = i4 * 4;
        in_[i + 0] = t.x + r0 * er_w[i + 0] + r1 * er_w[D + i + 0] + er_b[i + 0];
        in_[i + 1] = t.y + r0 * er_w[i + 1] + r1 * er_w[D + i + 1] + er_b[i + 1];
        in_[i + 2] = t.z + r0 * er_w[i + 2] + r1 * er_w[D + i + 2] + er_b[i + 2];
        in_[i + 3] = t.w + r0 * er_w[i + 3] + r1 * er_w[D + i + 3] + er_b[i + 3];
    }
    #pragma unroll
    for (int dd = 0; dd < D; ++dd) acc[dd] = mi_b2[dd];
    #pragma unroll 2
    for (int j = 0; j < 128; ++j) {
        float h = mi_b1[j];
        #pragma unroll
        for (int i = 0; i < D; ++i) h += in_[i] * mi_w1[i * 128 + j];
        h = fmaxf(h, 0.0f);
        #pragma unroll
        for (int dd = 0; dd < D; ++dd) acc[dd] += h * mi_w2[j * D + dd];
    }
    float4* vb = (float4*)(v_buf + ((size_t)bs * N + n) * D);
    #pragma unroll
    for (int dd = 0; dd < D; dd += 4)
        vb[dd >> 2] = make_float4(acc[dd], acc[dd + 1], acc[dd + 2], acc[dd + 3]);
}

// ---------------- K4: softmax over slots, renorm over n, calcSP -------------
__global__ __launch_bounds__(256) void attn_kernel(
    const float* __restrict__ logits,
    float* __restrict__ attn_out, float* __restrict__ s_p, float* __restrict__ s_s) {
    int b = blockIdx.x;
    int n = threadIdx.x;   // 0..255
    float a[S];
    const float* lr = logits + (b * N + n) * S;
    float m = -1e30f;
    #pragma unroll
    for (int s = 0; s < S; ++s) { a[s] = lr[s]; m = fmaxf(m, a[s]); }
    float sum = 0.f;
    #pragma unroll
    for (int s = 0; s < S; ++s) { a[s] = expf(a[s] - m); sum += a[s]; }
    float inv = 1.0f / sum;
    #pragma unroll
    for (int s = 0; s < S; ++s) a[s] = a[s] * inv + 1e-8f;

    __shared__ float cs[S];
    __shared__ float wp_l[S][2];
    __shared__ float ws_l[S][2];
    if (n < S) {
        cs[n] = 0.f;
        wp_l[n][0] = 0.f; wp_l[n][1] = 0.f;
        ws_l[n][0] = 0.f; ws_l[n][1] = 0.f;
    }
    __syncthreads();
    // column sums over n (renorm)
    #pragma unroll
    for (int s = 0; s < S; ++s) {
        float v = a[s];
        #pragma unroll
        for (int off = 32; off > 0; off >>= 1) v += __shfl_xor(v, off);
        if ((n & 63) == 0) atomicAdd(&cs[s], v);
    }
    __syncthreads();
    #pragma unroll
    for (int s = 0; s < S; ++s) a[s] /= cs[s];
    float* ao = attn_out + (b * N + n) * S;
    #pragma unroll
    for (int s = 0; s < S; ++s) ao[s] = a[s];

    // wp = sum_n grid * attn
    float g0 = grid_coord(n >> 4), g1 = grid_coord(n & 15);
    #pragma unroll
    for (int s = 0; s < S; ++s) {
        float c0 = a[s] * g0, c1 = a[s] * g1;
        #pragma unroll
        for (int off = 32; off > 0; off >>= 1) {
            c0 += __shfl_xor(c0, off); c1 += __shfl_xor(c1, off);
        }
        if ((n & 63) == 0) { atomicAdd(&wp_l[s][0], c0); atomicAdd(&wp_l[s][1], c1); }
    }
    __syncthreads();
    // ws = sqrt(sum_n (grid-wp)^2 * (attn+1e-11))
    #pragma unroll
    for (int s = 0; s < S; ++s) {
        float aw = a[s] + 1e-11f;
        float d0 = g0 - wp_l[s][0], d1 = g1 - wp_l[s][1];
        float c0 = d0 * d0 * aw, c1 = d1 * d1 * aw;
        #pragma unroll
        for (int off = 32; off > 0; off >>= 1) {
            c0 += __shfl_xor(c0, off); c1 += __shfl_xor(c1, off);
        }
        if ((n & 63) == 0) { atomicAdd(&ws_l[s][0], c0); atomicAdd(&ws_l[s][1], c1); }
    }
    __syncthreads();
    if (n < S) {
        s_p[(b * S + n) * 2 + 0] = wp_l[n][0];
        s_p[(b * S + n) * 2 + 1] = wp_l[n][1];
        float w0 = sqrtf(ws_l[n][0]), w1 = sqrtf(ws_l[n][1]);
        s_s[(b * S + n) * 2 + 0] = fminf(fmaxf(w0, 0.001f), 5.0f);
        s_s[(b * S + n) * 2 + 1] = fminf(fmaxf(w1, 0.001f), 5.0f);
    }
}

// ---------------- K5: updates = attn^T v ; GRU ; residual MLP ---------------
__global__ __launch_bounds__(64) void update_kernel(
    const float* __restrict__ attn, const float* __restrict__ v_buf,
    const float* __restrict__ gru_k, const float* __restrict__ gru_rk,
    const float* __restrict__ gru_b,
    const float* __restrict__ nm_g, const float* __restrict__ nm_b,
    const float* __restrict__ mlp_w1, const float* __restrict__ mlp_b1,
    const float* __restrict__ mlp_w2, const float* __restrict__ mlp_b2,
    float* __restrict__ slots) {
    int bs = blockIdx.x;        // 0..351
    int b = bs / S, s = bs % S;
    int d = threadIdx.x;
    const float* vrow = v_buf + (size_t)bs * N * D;
    float u = 0.f;
    for (int n = 0; n < N; ++n) {
        float a = attn[(b * N + n) * S + s];   // wave-uniform -> scalar load
        u += a * vrow[n * D + d];
    }
    __shared__ float ul[D], hl[D];
    float h = slots[bs * D + d];
    ul[d] = u; hl[d] = h;
    __syncthreads();
    float xz = gru_b[d], xr = gru_b[64 + d], xh = gru_b[128 + d];
    float hz = gru_b[192 + d], hr = gru_b[256 + d], hh = gru_b[320 + d];
    for (int i = 0; i < D; ++i) {
        float ui = ul[i], hi = hl[i];
        xz += ui * gru_k[i * 192 + d];
        xr += ui * gru_k[i * 192 + 64 + d];
        xh += ui * gru_k[i * 192 + 128 + d];
        hz += hi * gru_rk[i * 192 + d];
        hr += hi * gru_rk[i * 192 + 64 + d];
        hh += hi * gru_rk[i * 192 + 128 + d];
    }
    float z = 1.f / (1.f + expf(-(xz + hz)));
    float r = 1.f / (1.f + expf(-(xr + hr)));
    float hc = tanhf(xh + r * hh);
    float sn = z * h + (1.f - z) * hc;
    // LayerNorm(sn) with nm_g/nm_b
    float sum = sn;
    #pragma unroll
    for (int off = 32; off > 0; off >>= 1) sum += __shfl_xor(sum, off);
    float mm = sum * (1.0f / 64.0f);
    float dx = sn - mm;
    float vs = dx * dx;
    #pragma unroll
    for (int off = 32; off > 0; off >>= 1) vs += __shfl_xor(vs, off);
    float var = vs * (1.0f / 64.0f);
    float xln = dx * rsqrtf(var + LN_EPS) * nm_g[d] + nm_b[d];
    __shared__ float xl[D];
    __shared__ float hb[128];
    xl[d] = xln;
    __syncthreads();
    #pragma unroll
    for (int jj = 0; jj < 2; ++jj) {
        int j = jj * 64 + d;
        float h1 = mlp_b1[j];
        #pragma unroll 8
        for (int i = 0; i < D; ++i) h1 += xl[i] * mlp_w1[i * 128 + j];
        hb[j] = fmaxf(h1, 0.f);
    }
    __syncthreads();
    float o = mlp_b2[d];
    #pragma unroll 8
    for (int j = 0; j < 128; ++j) o += hb[j] * mlp_w2[j * D + d];
    slots[bs * D + d] = sn + o;
}

// ---------------- K6: copy slots, s_p, s_s to output ------------------------
__global__ void copyout_kernel(
    const float* __restrict__ slots, const float* __restrict__ s_p,
    const float* __restrict__ s_s, float* __restrict__ out) {
    int idx = blockIdx.x * blockDim.x + threadIdx.x;
    if (idx < B * S * D) out[idx] = slots[idx];
    else if (idx < B * S * D + B * S * 2) out[idx] = s_p[idx - B * S * D];
    else if (idx < B * S * D + 2 * B * S * 2) out[idx] = s_s[idx - B * S * D - B * S * 2];
}

extern "C" void kernel_launch(void* const* d_in, const int* in_sizes, int n_in,
                              void* d_out, int out_size, void* d_ws, size_t ws_size,
                              hipStream_t stream) {
    const float* inputs  = (const float*)d_in[0];
    const float* s_p0    = (const float*)d_in[1];
    const float* s_s0    = (const float*)d_in[2];
    const float* slots_mu= (const float*)d_in[3];
    const float* es_w1   = (const float*)d_in[4];
    const float* es_b1   = (const float*)d_in[5];
    const float* es_w2   = (const float*)d_in[6];
    const float* es_b2   = (const float*)d_in[7];
    const float* er_w    = (const float*)d_in[8];
    const float* er_b    = (const float*)d_in[9];
    const float* pk_w    = (const float*)d_in[10];
    const float* pk_b    = (const float*)d_in[11];
    const float* pv_w    = (const float*)d_in[12];
    const float* pv_b    = (const float*)d_in[13];
    const float* pq_w    = (const float*)d_in[14];
    const float* pq_b    = (const float*)d_in[15];
    const float* mi_w1   = (const float*)d_in[16];
    const float* mi_b1   = (const float*)d_in[17];
    const float* mi_w2   = (const float*)d_in[18];
    const float* mi_b2   = (const float*)d_in[19];
    const float* ns_g    = (const float*)d_in[20];
    const float* ns_b    = (const float*)d_in[21];
    const float* nm_g    = (const float*)d_in[22];
    const float* nm_b    = (const float*)d_in[23];
    const float* gru_k   = (const float*)d_in[24];
    const float* gru_rk  = (const float*)d_in[25];
    const float* gru_b   = (const float*)d_in[26];
    const float* mlp_w1  = (const float*)d_in[27];
    const float* mlp_b1  = (const float*)d_in[28];
    const float* mlp_w2  = (const float*)d_in[29];
    const float* mlp_b2  = (const float*)d_in[30];

    float* ws    = (float*)d_ws;
    float* pos   = ws;                      // 131072
    float* ik    = pos + 131072;            // 524288
    float* iv    = ik + 524288;             // 524288
    float* vb    = iv + 524288;             // 5767168
    float* lgts  = vb + 5767168;            // 360448
    float* q     = lgts + 360448;           // 22528
    float* slots = q + 22528;               // 22528
    float* sp    = slots + 22528;           // 704
    float* ssg   = sp + 704;                // 704

    float* out      = (float*)d_out;
    float* attn_out = out + B * S * D + 2 * B * S * 2;   // 23936

    pos_kernel<<<256, 128, 0, stream>>>(es_w1, es_b1, es_w2, es_b2, pos);
    init_kernel<<<88, 256, 0, stream>>>(slots_mu, s_p0, s_s0, slots, sp, ssg);
    projkv_kernel<<<256, 256, 0, stream>>>(inputs, pos, pk_w, pk_b, pv_w, pv_b, ik, iv);

    for (int ind = 0; ind < 4; ++ind) {
        q_kernel<<<352, 64, 0, stream>>>(slots, ns_g, ns_b, pq_w, pq_b, q);
        kv_kernel<<<704, 128, 0, stream>>>(ik, iv, sp, ssg, er_w, er_b,
                                           mi_w1, mi_b1, mi_w2, mi_b2, q, vb, lgts);
        attn_kernel<<<32, 256, 0, stream>>>(lgts, attn_out, sp, ssg);
        if (ind < 3)
            update_kernel<<<352, 64, 0, stream>>>(attn_out, vb, gru_k, gru_rk, gru_b,
                                                  nm_g, nm_b, mlp_w1, mlp_b1,
                                                  mlp_w2, mlp_b2, slots);
    }
    copyout_kernel<<<94, 256, 0, stream>>>(slots, sp, ssg, out);
}

// Round 2
// 474.052 us; speedup vs baseline: 3.0042x; 3.0042x over previous
//
#include <hip/hip_runtime.h>
#include <cmath>

#define B 32
#define S 11
#define R 16
#define D 64
#define C 512
#define N 256   // R*R
#define LN_EPS 1e-3f

typedef unsigned short u16;
typedef unsigned int   u32;

using bf16x8 = __attribute__((ext_vector_type(8))) short;
using f32x4  = __attribute__((ext_vector_type(4))) float;

__device__ __forceinline__ float grid_coord(int i) {
    return -1.0f + (2.0f / 15.0f) * (float)i;
}

__device__ __forceinline__ u16 f2bf(float x) {
    union { float f; u32 u; } c; c.f = x;
    u32 r = c.u + 0x7fffu + ((c.u >> 16) & 1u);   // RNE
    return (u16)(r >> 16);
}

// ---------------- K0: positional embedding pos[n, c] (once) ----------------
__global__ __launch_bounds__(128) void pos_kernel(
    const float* __restrict__ es_w1, const float* __restrict__ es_b1,
    const float* __restrict__ es_w2, const float* __restrict__ es_b2,
    float* __restrict__ pos) {
    int n = blockIdx.x;       // 0..255
    int j = threadIdx.x;      // 0..127
    float g0 = grid_coord(n >> 4), g1 = grid_coord(n & 15);
    __shared__ float h[128];
    float hj = es_b1[j] + g0 * es_w1[j] + g1 * es_w1[128 + j];
    h[j] = fmaxf(hj, 0.0f);
    __syncthreads();
    for (int c0 = 0; c0 < C; c0 += 128) {
        int c = c0 + j;
        float acc = es_b2[c];
        #pragma unroll 16
        for (int jj = 0; jj < 128; ++jj) acc += h[jj] * es_w2[jj * C + c];
        pos[n * C + c] = acc;
    }
}

// ---------------- K_init ----------------------------------------------------
__global__ void init_kernel(
    const float* __restrict__ slots_mu, const float* __restrict__ s_p0,
    const float* __restrict__ s_s0,
    float* __restrict__ slots, float* __restrict__ s_p, float* __restrict__ s_s) {
    int idx = blockIdx.x * blockDim.x + threadIdx.x;
    if (idx < B * S * D) slots[idx] = slots_mu[idx % (S * D)];
    if (idx < B * S * 2) { s_p[idx] = s_p0[idx]; s_s[idx] = s_s0[idx]; }
}

// ---------------- K1: inputs_k / inputs_v projection (once) -----------------
__global__ __launch_bounds__(256) void projkv_kernel(
    const float* __restrict__ inputs, const float* __restrict__ pos,
    const float* __restrict__ pk_w, const float* __restrict__ pk_b,
    const float* __restrict__ pv_w, const float* __restrict__ pv_b,
    float* __restrict__ ik, float* __restrict__ iv) {
    int b = blockIdx.x >> 3;
    int tile = blockIdx.x & 7;
    int n0 = tile * 32;
    int tid = threadIdx.x;
    int d = tid & 63;
    int wv = tid >> 6;
    __shared__ float xs[32][128];
    float accK[8], accV[8];
    #pragma unroll
    for (int r = 0; r < 8; ++r) { accK[r] = pk_b[d]; accV[r] = pv_b[d]; }
    for (int cc = 0; cc < C; cc += 128) {
        __syncthreads();
        for (int e = tid; e < 32 * 128; e += 256) {
            int row = e >> 7, col = e & 127;
            int n = n0 + row;
            xs[row][col] = inputs[(b * N + n) * C + cc + col] + pos[n * C + cc + col];
        }
        __syncthreads();
        for (int c = 0; c < 128; ++c) {
            float wk = pk_w[(cc + c) * D + d];
            float wvv = pv_w[(cc + c) * D + d];
            #pragma unroll
            for (int r = 0; r < 8; ++r) {
                float x = xs[wv * 8 + r][c];
                accK[r] += x * wk;
                accV[r] += x * wvv;
            }
        }
    }
    #pragma unroll
    for (int r = 0; r < 8; ++r) {
        int n = n0 + wv * 8 + r;
        ik[(b * N + n) * D + d] = accK[r];
        iv[(b * N + n) * D + d] = accV[r];
    }
}

// ---------------- K_wprep: transpose+cast MLP weights to bf16 (once) --------
__global__ __launch_bounds__(256) void wprep_kernel(
    const float* __restrict__ mi_w1, const float* __restrict__ mi_w2,
    u16* __restrict__ w1t, u16* __restrict__ w2t) {
    int idx = blockIdx.x * 256 + threadIdx.x;  // 0..16383
    if (idx < 8192) {
        int j = idx >> 6, k = idx & 63;        // w1t[j][k] = w1[k][j]
        w1t[idx] = f2bf(mi_w1[k * 128 + j]);
    } else {
        int i = idx - 8192;
        int dd = i >> 7, j = i & 127;          // w2t[d][j] = w2[j][d]
        w2t[i] = f2bf(mi_w2[j * 64 + dd]);
    }
}

// ---------------- K2: q = (LN(slots) @ pq_w + pq_b) * D^-0.5 ----------------
__global__ __launch_bounds__(64) void q_kernel(
    const float* __restrict__ slots,
    const float* __restrict__ ns_g, const float* __restrict__ ns_b,
    const float* __restrict__ pq_w, const float* __restrict__ pq_b,
    float* __restrict__ q) {
    int bs = blockIdx.x;
    int d = threadIdx.x;
    float x = slots[bs * D + d];
    float sum = x;
    #pragma unroll
    for (int off = 32; off > 0; off >>= 1) sum += __shfl_xor(sum, off);
    float m = sum * (1.0f / 64.0f);
    float dx = x - m;
    float vs = dx * dx;
    #pragma unroll
    for (int off = 32; off > 0; off >>= 1) vs += __shfl_xor(vs, off);
    float var = vs * (1.0f / 64.0f);
    float xln = dx * rsqrtf(var + LN_EPS) * ns_g[d] + ns_b[d];
    __shared__ float lds[64];
    lds[d] = xln;
    __syncthreads();
    float acc = pq_b[d];
    #pragma unroll 8
    for (int i = 0; i < 64; ++i) acc += lds[i] * pq_w[i * D + d];
    q[bs * D + d] = acc * 0.125f;
}

// ---------------- K2b: w2q[bs][j] = sum_d W2[j][d] q[bs][d]; b2q ------------
__global__ __launch_bounds__(128) void w2q_kernel(
    const float* __restrict__ mi_w2, const float* __restrict__ mi_b2,
    const float* __restrict__ q, float* __restrict__ w2q, float* __restrict__ b2q) {
    int bs = blockIdx.x;
    int j = threadIdx.x;   // 0..127
    const float* qb = q + bs * 64;
    float s = 0.f;
    #pragma unroll 8
    for (int d = 0; d < 64; ++d) s += mi_w2[j * 64 + d] * qb[d];
    w2q[bs * 128 + j] = s;
    if (j < 64) {
        float v = mi_b2[j] * qb[j];
        #pragma unroll
        for (int off = 32; off > 0; off >>= 1) v += __shfl_xor(v, off);
        if (j == 0) b2q[bs] = v;
    }
}

// ============ K3a: k path — layer1 MFMA + dot with w2q -> logits ============
// Layer1 computed transposed: Dt[j][row] = sum_k W1T[j][k] * X[row][k]
__global__ __launch_bounds__(256) void klogits_kernel(
    const float* __restrict__ ik,
    const float* __restrict__ s_p, const float* __restrict__ s_s,
    const float* __restrict__ er_w, const float* __restrict__ er_b,
    const u16* __restrict__ w1t, const float* __restrict__ mi_b1,
    const float* __restrict__ w2q, const float* __restrict__ b2q,
    float* __restrict__ logits) {
    int blk = blockIdx.x;       // 704
    int half = blk & 1;
    int bs = blk >> 1;
    int b = bs / S, s = bs % S;
    int tid = threadIdx.x;

    __shared__ u16 Xs[128 * 64];
    __shared__ u16 W1s[128 * 64];
    __shared__ float b1s[128];
    __shared__ float w2qs[128];

    // stage W1T (swizzled): 1024 chunks of 8 bf16
    const uint4* w1g = (const uint4*)w1t;
    for (int c = tid; c < 1024; c += 256) {
        int j = c >> 3, k0 = (c & 7) * 8;
        int ks = k0 ^ ((j & 7) << 3);
        *(uint4*)&W1s[j * 64 + ks] = w1g[c];
    }
    if (tid < 128) { b1s[tid] = mi_b1[tid]; w2qs[tid] = w2q[bs * 128 + tid]; }

    // stage X = ik + pe (bf16, swizzled); 2 threads per row
    {
        float p0 = s_p[bs * 2 + 0], p1 = s_p[bs * 2 + 1];
        float ss0 = s_s[bs * 2 + 0], ss1 = s_s[bs * 2 + 1];
        int row = tid >> 1;
        int kh = (tid & 1) * 32;
        int n = half * 128 + row;
        float g0 = grid_coord(n >> 4), g1 = grid_coord(n & 15);
        float r0 = (g0 - p0) / ss0, r1 = (g1 - p1) / ss1;
        const float4* src4 = (const float4*)(ik + (size_t)(b * N + n) * D + kh);
        #pragma unroll
        for (int c2 = 0; c2 < 4; ++c2) {
            int i0 = kh + c2 * 8;
            float4 ta = src4[c2 * 2 + 0];
            float4 tb = src4[c2 * 2 + 1];
            float v0 = ta.x + r0 * er_w[i0 + 0] + r1 * er_w[D + i0 + 0] + er_b[i0 + 0];
            float v1 = ta.y + r0 * er_w[i0 + 1] + r1 * er_w[D + i0 + 1] + er_b[i0 + 1];
            float v2 = ta.z + r0 * er_w[i0 + 2] + r1 * er_w[D + i0 + 2] + er_b[i0 + 2];
            float v3 = ta.w + r0 * er_w[i0 + 3] + r1 * er_w[D + i0 + 3] + er_b[i0 + 3];
            float v4 = tb.x + r0 * er_w[i0 + 4] + r1 * er_w[D + i0 + 4] + er_b[i0 + 4];
            float v5 = tb.y + r0 * er_w[i0 + 5] + r1 * er_w[D + i0 + 5] + er_b[i0 + 5];
            float v6 = tb.z + r0 * er_w[i0 + 6] + r1 * er_w[D + i0 + 6] + er_b[i0 + 6];
            float v7 = tb.w + r0 * er_w[i0 + 7] + r1 * er_w[D + i0 + 7] + er_b[i0 + 7];
            uint4 pk;
            pk.x = (u32)f2bf(v0) | ((u32)f2bf(v1) << 16);
            pk.y = (u32)f2bf(v2) | ((u32)f2bf(v3) << 16);
            pk.z = (u32)f2bf(v4) | ((u32)f2bf(v5) << 16);
            pk.w = (u32)f2bf(v6) | ((u32)f2bf(v7) << 16);
            int ks = i0 ^ ((row & 7) << 3);
            *(uint4*)&Xs[row * 64 + ks] = pk;
        }
    }
    __syncthreads();

    int w = tid >> 6;
    int l = tid & 63;
    int l16 = l & 15, lq = l >> 4;

    // B-frags: X rows (this wave's 32 rows)
    bf16x8 xb[2][2];
    #pragma unroll
    for (int rt = 0; rt < 2; ++rt) {
        int row = w * 32 + rt * 16 + l16;
        #pragma unroll
        for (int kt = 0; kt < 2; ++kt) {
            int k0 = kt * 32 + lq * 8;
            int ks = k0 ^ ((row & 7) << 3);
            xb[rt][kt] = *(const bf16x8*)&Xs[row * 64 + ks];
        }
    }
    f32x4 acc[8][2];
    #pragma unroll
    for (int jt = 0; jt < 8; ++jt)
        #pragma unroll
        for (int rt = 0; rt < 2; ++rt)
            acc[jt][rt] = (f32x4){0.f, 0.f, 0.f, 0.f};

    #pragma unroll
    for (int jt = 0; jt < 8; ++jt) {
        int j = jt * 16 + l16;
        int ks0 = (lq * 8) ^ ((j & 7) << 3);
        int ks1 = (32 + lq * 8) ^ ((j & 7) << 3);
        bf16x8 a0 = *(const bf16x8*)&W1s[j * 64 + ks0];
        bf16x8 a1 = *(const bf16x8*)&W1s[j * 64 + ks1];
        #pragma unroll
        for (int rt = 0; rt < 2; ++rt) {
            acc[jt][rt] = __builtin_amdgcn_mfma_f32_16x16x32_bf16(a0, xb[rt][0], acc[jt][rt], 0, 0, 0);
            acc[jt][rt] = __builtin_amdgcn_mfma_f32_16x16x32_bf16(a1, xb[rt][1], acc[jt][rt], 0, 0, 0);
        }
    }

    // logits[row] = sum_j relu(H^T[j][row] + b1[j]) * w2q[j] + b2q
    float part0 = 0.f, part1 = 0.f;
    #pragma unroll
    for (int jt = 0; jt < 8; ++jt) {
        float4 wq = *(const float4*)&w2qs[jt * 16 + lq * 4];
        float4 bb = *(const float4*)&b1s[jt * 16 + lq * 4];
        part0 += fmaxf(acc[jt][0][0] + bb.x, 0.f) * wq.x;
        part0 += fmaxf(acc[jt][0][1] + bb.y, 0.f) * wq.y;
        part0 += fmaxf(acc[jt][0][2] + bb.z, 0.f) * wq.z;
        part0 += fmaxf(acc[jt][0][3] + bb.w, 0.f) * wq.w;
        part1 += fmaxf(acc[jt][1][0] + bb.x, 0.f) * wq.x;
        part1 += fmaxf(acc[jt][1][1] + bb.y, 0.f) * wq.y;
        part1 += fmaxf(acc[jt][1][2] + bb.z, 0.f) * wq.z;
        part1 += fmaxf(acc[jt][1][3] + bb.w, 0.f) * wq.w;
    }
    part0 += __shfl_xor(part0, 16); part0 += __shfl_xor(part0, 32);
    part1 += __shfl_xor(part1, 16); part1 += __shfl_xor(part1, 32);
    if (lq == 0) {
        float bq = b2q[bs];
        int n0 = half * 128 + w * 32;
        logits[(size_t)(b * N + n0 + l16) * S + s]      = part0 + bq;
        logits[(size_t)(b * N + n0 + 16 + l16) * S + s] = part1 + bq;
    }
}

// ============ K3b: v path — layer1 MFMA -> H(LDS) -> layer2 MFMA -> v_buf ===
__global__ __launch_bounds__(256) void vff_kernel(
    const float* __restrict__ iv,
    const float* __restrict__ s_p, const float* __restrict__ s_s,
    const float* __restrict__ er_w, const float* __restrict__ er_b,
    const u16* __restrict__ w1t, const float* __restrict__ mi_b1,
    const u16* __restrict__ w2t, const float* __restrict__ mi_b2,
    float* __restrict__ v_buf) {
    int blk = blockIdx.x;
    int half = blk & 1;
    int bs = blk >> 1;
    int b = bs / S;
    int tid = threadIdx.x;

    __shared__ u16 Xs[128 * 64];
    __shared__ u16 W1s[128 * 64];
    __shared__ u16 W2s[64 * 128];
    __shared__ u16 Hs[128 * 128];
    __shared__ float b1s[128];

    const uint4* w1g = (const uint4*)w1t;
    const uint4* w2g = (const uint4*)w2t;
    for (int c = tid; c < 1024; c += 256) {
        int j = c >> 3, k0 = (c & 7) * 8;
        int ks = k0 ^ ((j & 7) << 3);
        *(uint4*)&W1s[j * 64 + ks] = w1g[c];
        int dd = c >> 4, k2 = (c & 15) * 8;
        int ks2 = k2 ^ ((dd & 15) << 3);
        *(uint4*)&W2s[dd * 128 + ks2] = w2g[c];
    }
    if (tid < 128) b1s[tid] = mi_b1[tid];

    {
        float p0 = s_p[bs * 2 + 0], p1 = s_p[bs * 2 + 1];
        float ss0 = s_s[bs * 2 + 0], ss1 = s_s[bs * 2 + 1];
        int row = tid >> 1;
        int kh = (tid & 1) * 32;
        int n = half * 128 + row;
        float g0 = grid_coord(n >> 4), g1 = grid_coord(n & 15);
        float r0 = (g0 - p0) / ss0, r1 = (g1 - p1) / ss1;
        const float4* src4 = (const float4*)(iv + (size_t)(b * N + n) * D + kh);
        #pragma unroll
        for (int c2 = 0; c2 < 4; ++c2) {
            int i0 = kh + c2 * 8;
            float4 ta = src4[c2 * 2 + 0];
            float4 tb = src4[c2 * 2 + 1];
            float v0 = ta.x + r0 * er_w[i0 + 0] + r1 * er_w[D + i0 + 0] + er_b[i0 + 0];
            float v1 = ta.y + r0 * er_w[i0 + 1] + r1 * er_w[D + i0 + 1] + er_b[i0 + 1];
            float v2 = ta.z + r0 * er_w[i0 + 2] + r1 * er_w[D + i0 + 2] + er_b[i0 + 2];
            float v3 = ta.w + r0 * er_w[i0 + 3] + r1 * er_w[D + i0 + 3] + er_b[i0 + 3];
            float v4 = tb.x + r0 * er_w[i0 + 4] + r1 * er_w[D + i0 + 4] + er_b[i0 + 4];
            float v5 = tb.y + r0 * er_w[i0 + 5] + r1 * er_w[D + i0 + 5] + er_b[i0 + 5];
            float v6 = tb.z + r0 * er_w[i0 + 6] + r1 * er_w[D + i0 + 6] + er_b[i0 + 6];
            float v7 = tb.w + r0 * er_w[i0 + 7] + r1 * er_w[D + i0 + 7] + er_b[i0 + 7];
            uint4 pk;
            pk.x = (u32)f2bf(v0) | ((u32)f2bf(v1) << 16);
            pk.y = (u32)f2bf(v2) | ((u32)f2bf(v3) << 16);
            pk.z = (u32)f2bf(v4) | ((u32)f2bf(v5) << 16);
            pk.w = (u32)f2bf(v6) | ((u32)f2bf(v7) << 16);
            int ks = i0 ^ ((row & 7) << 3);
            *(uint4*)&Xs[row * 64 + ks] = pk;
        }
    }
    __syncthreads();

    int w = tid >> 6;
    int l = tid & 63;
    int l16 = l & 15, lq = l >> 4;

    bf16x8 xb[2][2];
    #pragma unroll
    for (int rt = 0; rt < 2; ++rt) {
        int row = w * 32 + rt * 16 + l16;
        #pragma unroll
        for (int kt = 0; kt < 2; ++kt) {
            int k0 = kt * 32 + lq * 8;
            int ks = k0 ^ ((row & 7) << 3);
            xb[rt][kt] = *(const bf16x8*)&Xs[row * 64 + ks];
        }
    }
    f32x4 acc[8][2];
    #pragma unroll
    for (int jt = 0; jt < 8; ++jt)
        #pragma unroll
        for (int rt = 0; rt < 2; ++rt)
            acc[jt][rt] = (f32x4){0.f, 0.f, 0.f, 0.f};

    #pragma unroll
    for (int jt = 0; jt < 8; ++jt) {
        int j = jt * 16 + l16;
        int ks0 = (lq * 8) ^ ((j & 7) << 3);
        int ks1 = (32 + lq * 8) ^ ((j & 7) << 3);
        bf16x8 a0 = *(const bf16x8*)&W1s[j * 64 + ks0];
        bf16x8 a1 = *(const bf16x8*)&W1s[j * 64 + ks1];
        #pragma unroll
        for (int rt = 0; rt < 2; ++rt) {
            acc[jt][rt] = __builtin_amdgcn_mfma_f32_16x16x32_bf16(a0, xb[rt][0], acc[jt][rt], 0, 0, 0);
            acc[jt][rt] = __builtin_amdgcn_mfma_f32_16x16x32_bf16(a1, xb[rt][1], acc[jt][rt], 0, 0, 0);
        }
    }

    // H[row][j] = relu(acc + b1) -> LDS (bf16, swizzled), packed b64 writes
    #pragma unroll
    for (int jt = 0; jt < 8; ++jt) {
        float4 bb = *(const float4*)&b1s[jt * 16 + lq * 4];
        #pragma unroll
        for (int rt = 0; rt < 2; ++rt) {
            int row = w * 32 + rt * 16 + l16;
            float h0 = fmaxf(acc[jt][rt][0] + bb.x, 0.f);
            float h1 = fmaxf(acc[jt][rt][1] + bb.y, 0.f);
            float h2 = fmaxf(acc[jt][rt][2] + bb.z, 0.f);
            float h3 = fmaxf(acc[jt][rt][3] + bb.w, 0.f);
            u32 p0 = (u32)f2bf(h0) | ((u32)f2bf(h1) << 16);
            u32 p1 = (u32)f2bf(h2) | ((u32)f2bf(h3) << 16);
            int j0 = jt * 16 + lq * 4;
            int js = j0 ^ ((row & 15) << 3);
            *(uint2*)&Hs[row * 128 + js] = make_uint2(p0, p1);
        }
    }
    __syncthreads();

    // layer2: Y[row][d] = sum_j H[row][j] * W2T[d][j]
    f32x4 acc2[2][4];
    #pragma unroll
    for (int mt = 0; mt < 2; ++mt)
        #pragma unroll
        for (int nt = 0; nt < 4; ++nt)
            acc2[mt][nt] = (f32x4){0.f, 0.f, 0.f, 0.f};

    #pragma unroll
    for (int kt = 0; kt < 4; ++kt) {
        bf16x8 af[2], bw[4];
        #pragma unroll
        for (int mt = 0; mt < 2; ++mt) {
            int row = w * 32 + mt * 16 + l16;
            int js = (kt * 32 + lq * 8) ^ ((row & 15) << 3);
            af[mt] = *(const bf16x8*)&Hs[row * 128 + js];
        }
        #pragma unroll
        for (int nt = 0; nt < 4; ++nt) {
            int dd = nt * 16 + l16;
            int ks = (kt * 32 + lq * 8) ^ ((dd & 15) << 3);
            bw[nt] = *(const bf16x8*)&W2s[dd * 128 + ks];
        }
        #pragma unroll
        for (int mt = 0; mt < 2; ++mt)
            #pragma unroll
            for (int nt = 0; nt < 4; ++nt)
                acc2[mt][nt] = __builtin_amdgcn_mfma_f32_16x16x32_bf16(af[mt], bw[nt], acc2[mt][nt], 0, 0, 0);
    }

    #pragma unroll
    for (int nt = 0; nt < 4; ++nt) {
        float b2v = mi_b2[nt * 16 + l16];
        #pragma unroll
        for (int mt = 0; mt < 2; ++mt) {
            #pragma unroll
            for (int r = 0; r < 4; ++r) {
                int n = half * 128 + w * 32 + mt * 16 + lq * 4 + r;
                v_buf[((size_t)bs * N + n) * D + nt * 16 + l16] = acc2[mt][nt][r] + b2v;
            }
        }
    }
}

// ---------------- K4: softmax over slots, renorm over n, calcSP -------------
__global__ __launch_bounds__(256) void attn_kernel(
    const float* __restrict__ logits,
    float* __restrict__ attn_out, float* __restrict__ s_p, float* __restrict__ s_s) {
    int b = blockIdx.x;
    int n = threadIdx.x;
    float a[S];
    const float* lr = logits + (b * N + n) * S;
    float m = -1e30f;
    #pragma unroll
    for (int s = 0; s < S; ++s) { a[s] = lr[s]; m = fmaxf(m, a[s]); }
    float sum = 0.f;
    #pragma unroll
    for (int s = 0; s < S; ++s) { a[s] = expf(a[s] - m); sum += a[s]; }
    float inv = 1.0f / sum;
    #pragma unroll
    for (int s = 0; s < S; ++s) a[s] = a[s] * inv + 1e-8f;

    __shared__ float cs[S];
    __shared__ float wp_l[S][2];
    __shared__ float ws_l[S][2];
    if (n < S) {
        cs[n] = 0.f;
        wp_l[n][0] = 0.f; wp_l[n][1] = 0.f;
        ws_l[n][0] = 0.f; ws_l[n][1] = 0.f;
    }
    __syncthreads();
    #pragma unroll
    for (int s = 0; s < S; ++s) {
        float v = a[s];
        #pragma unroll
        for (int off = 32; off > 0; off >>= 1) v += __shfl_xor(v, off);
        if ((n & 63) == 0) atomicAdd(&cs[s], v);
    }
    __syncthreads();
    #pragma unroll
    for (int s = 0; s < S; ++s) a[s] /= cs[s];
    float* ao = attn_out + (b * N + n) * S;
    #pragma unroll
    for (int s = 0; s < S; ++s) ao[s] = a[s];

    float g0 = grid_coord(n >> 4), g1 = grid_coord(n & 15);
    #pragma unroll
    for (int s = 0; s < S; ++s) {
        float c0 = a[s] * g0, c1 = a[s] * g1;
        #pragma unroll
        for (int off = 32; off > 0; off >>= 1) {
            c0 += __shfl_xor(c0, off); c1 += __shfl_xor(c1, off);
        }
        if ((n & 63) == 0) { atomicAdd(&wp_l[s][0], c0); atomicAdd(&wp_l[s][1], c1); }
    }
    __syncthreads();
    #pragma unroll
    for (int s = 0; s < S; ++s) {
        float aw = a[s] + 1e-11f;
        float d0 = g0 - wp_l[s][0], d1 = g1 - wp_l[s][1];
        float c0 = d0 * d0 * aw, c1 = d1 * d1 * aw;
        #pragma unroll
        for (int off = 32; off > 0; off >>= 1) {
            c0 += __shfl_xor(c0, off); c1 += __shfl_xor(c1, off);
        }
        if ((n & 63) == 0) { atomicAdd(&ws_l[s][0], c0); atomicAdd(&ws_l[s][1], c1); }
    }
    __syncthreads();
    if (n < S) {
        s_p[(b * S + n) * 2 + 0] = wp_l[n][0];
        s_p[(b * S + n) * 2 + 1] = wp_l[n][1];
        float w0 = sqrtf(ws_l[n][0]), w1 = sqrtf(ws_l[n][1]);
        s_s[(b * S + n) * 2 + 0] = fminf(fmaxf(w0, 0.001f), 5.0f);
        s_s[(b * S + n) * 2 + 1] = fminf(fmaxf(w1, 0.001f), 5.0f);
    }
}

// ---------------- K5: updates = attn^T v ; GRU ; residual MLP ---------------
__global__ __launch_bounds__(64) void update_kernel(
    const float* __restrict__ attn, const float* __restrict__ v_buf,
    const float* __restrict__ gru_k, const float* __restrict__ gru_rk,
    const float* __restrict__ gru_b,
    const float* __restrict__ nm_g, const float* __restrict__ nm_b,
    const float* __restrict__ mlp_w1, const float* __restrict__ mlp_b1,
    const float* __restrict__ mlp_w2, const float* __restrict__ mlp_b2,
    float* __restrict__ slots) {
    int bs = blockIdx.x;
    int b = bs / S, s = bs % S;
    int d = threadIdx.x;
    const float* vrow = v_buf + (size_t)bs * N * D;
    float u = 0.f;
    for (int n = 0; n < N; ++n) {
        float a = attn[(b * N + n) * S + s];
        u += a * vrow[n * D + d];
    }
    __shared__ float ul[D], hl[D];
    float h = slots[bs * D + d];
    ul[d] = u; hl[d] = h;
    __syncthreads();
    float xz = gru_b[d], xr = gru_b[64 + d], xh = gru_b[128 + d];
    float hz = gru_b[192 + d], hr = gru_b[256 + d], hh = gru_b[320 + d];
    for (int i = 0; i < D; ++i) {
        float ui = ul[i], hi = hl[i];
        xz += ui * gru_k[i * 192 + d];
        xr += ui * gru_k[i * 192 + 64 + d];
        xh += ui * gru_k[i * 192 + 128 + d];
        hz += hi * gru_rk[i * 192 + d];
        hr += hi * gru_rk[i * 192 + 64 + d];
        hh += hi * gru_rk[i * 192 + 128 + d];
    }
    float z = 1.f / (1.f + expf(-(xz + hz)));
    float r = 1.f / (1.f + expf(-(xr + hr)));
    float hc = tanhf(xh + r * hh);
    float sn = z * h + (1.f - z) * hc;
    float sum = sn;
    #pragma unroll
    for (int off = 32; off > 0; off >>= 1) sum += __shfl_xor(sum, off);
    float mm = sum * (1.0f / 64.0f);
    float dx = sn - mm;
    float vs = dx * dx;
    #pragma unroll
    for (int off = 32; off > 0; off >>= 1) vs += __shfl_xor(vs, off);
    float var = vs * (1.0f / 64.0f);
    float xln = dx * rsqrtf(var + LN_EPS) * nm_g[d] + nm_b[d];
    __shared__ float xl[D];
    __shared__ float hb[128];
    xl[d] = xln;
    __syncthreads();
    #pragma unroll
    for (int jj = 0; jj < 2; ++jj) {
        int j = jj * 64 + d;
        float h1 = mlp_b1[j];
        #pragma unroll 8
        for (int i = 0; i < D; ++i) h1 += xl[i] * mlp_w1[i * 128 + j];
        hb[j] = fmaxf(h1, 0.f);
    }
    __syncthreads();
    float o = mlp_b2[d];
    #pragma unroll 8
    for (int j = 0; j < 128; ++j) o += hb[j] * mlp_w2[j * D + d];
    slots[bs * D + d] = sn + o;
}

// ---------------- K6: copy slots, s_p, s_s to output ------------------------
__global__ void copyout_kernel(
    const float* __restrict__ slots, const float* __restrict__ s_p,
    const float* __restrict__ s_s, float* __restrict__ out) {
    int idx = blockIdx.x * blockDim.x + threadIdx.x;
    if (idx < B * S * D) out[idx] = slots[idx];
    else if (idx < B * S * D + B * S * 2) out[idx] = s_p[idx - B * S * D];
    else if (idx < B * S * D + 2 * B * S * 2) out[idx] = s_s[idx - B * S * D - B * S * 2];
}

extern "C" void kernel_launch(void* const* d_in, const int* in_sizes, int n_in,
                              void* d_out, int out_size, void* d_ws, size_t ws_size,
                              hipStream_t stream) {
    const float* inputs  = (const float*)d_in[0];
    const float* s_p0    = (const float*)d_in[1];
    const float* s_s0    = (const float*)d_in[2];
    const float* slots_mu= (const float*)d_in[3];
    const float* es_w1   = (const float*)d_in[4];
    const float* es_b1   = (const float*)d_in[5];
    const float* es_w2   = (const float*)d_in[6];
    const float* es_b2   = (const float*)d_in[7];
    const float* er_w    = (const float*)d_in[8];
    const float* er_b    = (const float*)d_in[9];
    const float* pk_w    = (const float*)d_in[10];
    const float* pk_b    = (const float*)d_in[11];
    const float* pv_w    = (const float*)d_in[12];
    const float* pv_b    = (const float*)d_in[13];
    const float* pq_w    = (const float*)d_in[14];
    const float* pq_b    = (const float*)d_in[15];
    const float* mi_w1   = (const float*)d_in[16];
    const float* mi_b1   = (const float*)d_in[17];
    const float* mi_w2   = (const float*)d_in[18];
    const float* mi_b2   = (const float*)d_in[19];
    const float* ns_g    = (const float*)d_in[20];
    const float* ns_b    = (const float*)d_in[21];
    const float* nm_g    = (const float*)d_in[22];
    const float* nm_b    = (const float*)d_in[23];
    const float* gru_k   = (const float*)d_in[24];
    const float* gru_rk  = (const float*)d_in[25];
    const float* gru_b   = (const float*)d_in[26];
    const float* mlp_w1  = (const float*)d_in[27];
    const float* mlp_b1  = (const float*)d_in[28];
    const float* mlp_w2  = (const float*)d_in[29];
    const float* mlp_b2  = (const float*)d_in[30];

    float* ws    = (float*)d_ws;
    float* pos   = ws;                      // 131072 floats; reused after projkv:
    u16*   w1t   = (u16*)pos;               //   8192 u16 (4096 floats)
    u16*   w2t   = (u16*)(pos + 4096);      //   8192 u16
    float* w2qb  = pos + 8192;              //   45056 floats
    float* b2qb  = pos + 53248;             //   352 floats
    float* ik    = pos + 131072;            // 524288
    float* iv    = ik + 524288;             // 524288
    float* vb    = iv + 524288;             // 5767168
    float* lgts  = vb + 5767168;            // 360448
    float* q     = lgts + 360448;           // 22528
    float* slots = q + 22528;               // 22528
    float* sp    = slots + 22528;           // 704
    float* ssg   = sp + 704;                // 704

    float* out      = (float*)d_out;
    float* attn_out = out + B * S * D + 2 * B * S * 2;

    pos_kernel<<<256, 128, 0, stream>>>(es_w1, es_b1, es_w2, es_b2, pos);
    init_kernel<<<88, 256, 0, stream>>>(slots_mu, s_p0, s_s0, slots, sp, ssg);
    projkv_kernel<<<256, 256, 0, stream>>>(inputs, pos, pk_w, pk_b, pv_w, pv_b, ik, iv);
    wprep_kernel<<<64, 256, 0, stream>>>(mi_w1, mi_w2, w1t, w2t);   // pos region now free

    for (int ind = 0; ind < 4; ++ind) {
        q_kernel<<<352, 64, 0, stream>>>(slots, ns_g, ns_b, pq_w, pq_b, q);
        w2q_kernel<<<352, 128, 0, stream>>>(mi_w2, mi_b2, q, w2qb, b2qb);
        klogits_kernel<<<704, 256, 0, stream>>>(ik, sp, ssg, er_w, er_b,
                                                w1t, mi_b1, w2qb, b2qb, lgts);
        vff_kernel<<<704, 256, 0, stream>>>(iv, sp, ssg, er_w, er_b,
                                            w1t, mi_b1, w2t, mi_b2, vb);
        attn_kernel<<<32, 256, 0, stream>>>(lgts, attn_out, sp, ssg);
        if (ind < 3)
            update_kernel<<<352, 64, 0, stream>>>(attn_out, vb, gru_k, gru_rk, gru_b,
                                                  nm_g, nm_b, mlp_w1, mlp_b1,
                                                  mlp_w2, mlp_b2, slots);
    }
    copyout_kernel<<<94, 256, 0, stream>>>(slots, sp, ssg, out);
}

// Round 3
// 362.724 us; speedup vs baseline: 3.9262x; 1.3069x over previous
//
#include <hip/hip_runtime.h>
#include <cmath>

#define B 32
#define S 11
#define R 16
#define D 64
#define C 512
#define N 256   // R*R
#define LN_EPS 1e-3f

typedef unsigned short u16;
typedef unsigned int   u32;

using bf16x8 = __attribute__((ext_vector_type(8))) short;
using f32x4  = __attribute__((ext_vector_type(4))) float;

__device__ __forceinline__ float grid_coord(int i) {
    return -1.0f + (2.0f / 15.0f) * (float)i;
}

__device__ __forceinline__ u16 f2bf(float x) {
    union { float f; u32 u; } c; c.f = x;
    u32 r = c.u + 0x7fffu + ((c.u >> 16) & 1u);   // RNE
    return (u16)(r >> 16);
}

__device__ __forceinline__ float bf2f(u16 h) {
    union { u32 u; float f; } c; c.u = ((u32)h) << 16; return c.f;
}

// ---------------- K0: positional embedding pos[n, c] (once) ----------------
__global__ __launch_bounds__(128) void pos_kernel(
    const float* __restrict__ es_w1, const float* __restrict__ es_b1,
    const float* __restrict__ es_w2, const float* __restrict__ es_b2,
    float* __restrict__ pos) {
    int n = blockIdx.x;       // 0..255
    int j = threadIdx.x;      // 0..127
    float g0 = grid_coord(n >> 4), g1 = grid_coord(n & 15);
    __shared__ float h[128];
    float hj = es_b1[j] + g0 * es_w1[j] + g1 * es_w1[128 + j];
    h[j] = fmaxf(hj, 0.0f);
    __syncthreads();
    for (int c0 = 0; c0 < C; c0 += 128) {
        int c = c0 + j;
        float acc = es_b2[c];
        #pragma unroll 16
        for (int jj = 0; jj < 128; ++jj) acc += h[jj] * es_w2[jj * C + c];
        pos[n * C + c] = acc;
    }
}

// ---------------- K_init ----------------------------------------------------
__global__ void init_kernel(
    const float* __restrict__ slots_mu, const float* __restrict__ s_p0,
    const float* __restrict__ s_s0,
    float* __restrict__ slots, float* __restrict__ s_p, float* __restrict__ s_s) {
    int idx = blockIdx.x * blockDim.x + threadIdx.x;
    if (idx < B * S * D) slots[idx] = slots_mu[idx % (S * D)];
    if (idx < B * S * 2) { s_p[idx] = s_p0[idx]; s_s[idx] = s_s0[idx]; }
}

// ---------------- K_wprep: weight prep (once) -------------------------------
// w1t[j][k]=w1[k][j] bf16; w2t[d][j]=w2[j][d] bf16;
// wkvT hi/lo: col j<64 -> pk_w[:,j], j>=64 -> pv_w[:,j-64]; [128][512] split bf16
__global__ __launch_bounds__(256) void wprep_kernel(
    const float* __restrict__ mi_w1, const float* __restrict__ mi_w2,
    const float* __restrict__ pk_w, const float* __restrict__ pv_w,
    u16* __restrict__ w1t, u16* __restrict__ w2t,
    u16* __restrict__ wkvh, u16* __restrict__ wkvl) {
    int idx = blockIdx.x * 256 + threadIdx.x;  // 0..81919
    if (idx < 8192) {
        int j = idx >> 6, k = idx & 63;
        w1t[idx] = f2bf(mi_w1[k * 128 + j]);
    } else if (idx < 16384) {
        int i = idx - 8192;
        int dd = i >> 7, j = i & 127;
        w2t[i] = f2bf(mi_w2[j * 64 + dd]);
    } else {
        int i = idx - 16384;      // 0..65535 = j*512 + k
        int j = i >> 9, k = i & 511;
        float w = (j < 64) ? pk_w[k * 64 + j] : pv_w[k * 64 + (j - 64)];
        u16 h = f2bf(w);
        wkvh[i] = h;
        wkvl[i] = f2bf(w - bf2f(h));
    }
}

// ---------------- K1: inputs_k / inputs_v projection via MFMA (once) --------
// out[row][col] = sum_c (inputs+pos)[row][c] * Wkv[c][col], col<64->ik, >=64->iv
// hi/lo split on both operands (hh + hl + lh) for ~fp32 accuracy.
__global__ __launch_bounds__(64) void projkv_kernel(
    const float* __restrict__ inputs, const float* __restrict__ pos,
    const u16* __restrict__ wkvh, const u16* __restrict__ wkvl,
    const float* __restrict__ pk_b, const float* __restrict__ pv_b,
    float* __restrict__ ik, float* __restrict__ iv) {
    int n0 = blockIdx.x * 16;          // 512 blocks, 16 rows each
    int l = threadIdx.x;
    int l16 = l & 15, lq = l >> 4;
    int row = n0 + l16;
    const float* xin  = inputs + (size_t)row * C;
    const float* xpos = pos + (size_t)(row & (N - 1)) * C;

    f32x4 acc[8];
    #pragma unroll
    for (int nt = 0; nt < 8; ++nt) acc[nt] = (f32x4){0.f, 0.f, 0.f, 0.f};

    #pragma unroll 2
    for (int kc = 0; kc < 16; ++kc) {
        int k0 = kc * 32 + lq * 8;
        float4 a0 = *(const float4*)(xin + k0);
        float4 a1 = *(const float4*)(xin + k0 + 4);
        float4 p0 = *(const float4*)(xpos + k0);
        float4 p1 = *(const float4*)(xpos + k0 + 4);
        float x[8];
        x[0] = a0.x + p0.x; x[1] = a0.y + p0.y; x[2] = a0.z + p0.z; x[3] = a0.w + p0.w;
        x[4] = a1.x + p1.x; x[5] = a1.y + p1.y; x[6] = a1.z + p1.z; x[7] = a1.w + p1.w;
        union { bf16x8 v; u16 s[8]; } Ah, Al;
        #pragma unroll
        for (int i = 0; i < 8; ++i) {
            u16 h = f2bf(x[i]);
            Ah.s[i] = h;
            Al.s[i] = f2bf(x[i] - bf2f(h));
        }
        #pragma unroll
        for (int nt = 0; nt < 8; ++nt) {
            int col = nt * 16 + l16;
            bf16x8 bh = *(const bf16x8*)(wkvh + col * 512 + k0);
            bf16x8 bl = *(const bf16x8*)(wkvl + col * 512 + k0);
            acc[nt] = __builtin_amdgcn_mfma_f32_16x16x32_bf16(Ah.v, bh, acc[nt], 0, 0, 0);
            acc[nt] = __builtin_amdgcn_mfma_f32_16x16x32_bf16(Al.v, bh, acc[nt], 0, 0, 0);
            acc[nt] = __builtin_amdgcn_mfma_f32_16x16x32_bf16(Ah.v, bl, acc[nt], 0, 0, 0);
        }
    }
    #pragma unroll
    for (int nt = 0; nt < 8; ++nt) {
        int d = (nt & 3) * 16 + l16;
        float bias = (nt < 4) ? pk_b[d] : pv_b[d];
        float* dst = (nt < 4) ? ik : iv;
        #pragma unroll
        for (int r = 0; r < 4; ++r) {
            int n = n0 + lq * 4 + r;
            dst[(size_t)n * D + d] = acc[nt][r] + bias;
        }
    }
}

// ---------------- K2: q = LN(slots)@pq_w, then w2q = W2@q, b2q --------------
__global__ __launch_bounds__(128) void qw2q_kernel(
    const float* __restrict__ slots,
    const float* __restrict__ ns_g, const float* __restrict__ ns_b,
    const float* __restrict__ pq_w, const float* __restrict__ pq_b,
    const float* __restrict__ mi_w2, const float* __restrict__ mi_b2,
    float* __restrict__ w2q, float* __restrict__ b2q) {
    int bs = blockIdx.x;
    int t = threadIdx.x;
    __shared__ float xlds[64], qs[64];
    if (t < 64) {
        float x = slots[bs * D + t];
        float sum = x;
        #pragma unroll
        for (int off = 32; off > 0; off >>= 1) sum += __shfl_xor(sum, off);
        float m = sum * (1.0f / 64.0f);
        float dx = x - m;
        float vs = dx * dx;
        #pragma unroll
        for (int off = 32; off > 0; off >>= 1) vs += __shfl_xor(vs, off);
        float var = vs * (1.0f / 64.0f);
        xlds[t] = dx * rsqrtf(var + LN_EPS) * ns_g[t] + ns_b[t];
    }
    __syncthreads();
    if (t < 64) {
        float acc = pq_b[t];
        #pragma unroll 8
        for (int i = 0; i < 64; ++i) acc += xlds[i] * pq_w[i * D + t];
        qs[t] = acc * 0.125f;
    }
    __syncthreads();
    {
        float s = 0.f;
        #pragma unroll 8
        for (int dd = 0; dd < 64; ++dd) s += mi_w2[t * 64 + dd] * qs[dd];
        w2q[bs * 128 + t] = s;
    }
    if (t < 64) {
        float v = mi_b2[t] * qs[t];
        #pragma unroll
        for (int off = 32; off > 0; off >>= 1) v += __shfl_xor(v, off);
        if (t == 0) b2q[bs] = v;
    }
}

// ============ K3a: k path — layer1 MFMA + dot with w2q -> logits ============
__global__ __launch_bounds__(256) void klogits_kernel(
    const float* __restrict__ ik,
    const float* __restrict__ s_p, const float* __restrict__ s_s,
    const float* __restrict__ er_w, const float* __restrict__ er_b,
    const u16* __restrict__ w1t, const float* __restrict__ mi_b1,
    const float* __restrict__ w2q, const float* __restrict__ b2q,
    float* __restrict__ logits) {
    int blk = blockIdx.x;       // 704
    int half = blk & 1;
    int bs = blk >> 1;
    int b = bs / S, s = bs % S;
    int tid = threadIdx.x;

    __shared__ u16 Xs[128 * 64];
    __shared__ u16 W1s[128 * 64];
    __shared__ float b1s[128];
    __shared__ float w2qs[128];

    const uint4* w1g = (const uint4*)w1t;
    for (int c = tid; c < 1024; c += 256) {
        int j = c >> 3, k0 = (c & 7) * 8;
        int ks = k0 ^ ((j & 7) << 3);
        *(uint4*)&W1s[j * 64 + ks] = w1g[c];
    }
    if (tid < 128) { b1s[tid] = mi_b1[tid]; w2qs[tid] = w2q[bs * 128 + tid]; }

    {
        float p0 = s_p[bs * 2 + 0], p1 = s_p[bs * 2 + 1];
        float ss0 = s_s[bs * 2 + 0], ss1 = s_s[bs * 2 + 1];
        int row = tid >> 1;
        int kh = (tid & 1) * 32;
        int n = half * 128 + row;
        float g0 = grid_coord(n >> 4), g1 = grid_coord(n & 15);
        float r0 = (g0 - p0) / ss0, r1 = (g1 - p1) / ss1;
        const float4* src4 = (const float4*)(ik + (size_t)(b * N + n) * D + kh);
        #pragma unroll
        for (int c2 = 0; c2 < 4; ++c2) {
            int i0 = kh + c2 * 8;
            float4 ta = src4[c2 * 2 + 0];
            float4 tb = src4[c2 * 2 + 1];
            float v0 = ta.x + r0 * er_w[i0 + 0] + r1 * er_w[D + i0 + 0] + er_b[i0 + 0];
            float v1 = ta.y + r0 * er_w[i0 + 1] + r1 * er_w[D + i0 + 1] + er_b[i0 + 1];
            float v2 = ta.z + r0 * er_w[i0 + 2] + r1 * er_w[D + i0 + 2] + er_b[i0 + 2];
            float v3 = ta.w + r0 * er_w[i0 + 3] + r1 * er_w[D + i0 + 3] + er_b[i0 + 3];
            float v4 = tb.x + r0 * er_w[i0 + 4] + r1 * er_w[D + i0 + 4] + er_b[i0 + 4];
            float v5 = tb.y + r0 * er_w[i0 + 5] + r1 * er_w[D + i0 + 5] + er_b[i0 + 5];
            float v6 = tb.z + r0 * er_w[i0 + 6] + r1 * er_w[D + i0 + 6] + er_b[i0 + 6];
            float v7 = tb.w + r0 * er_w[i0 + 7] + r1 * er_w[D + i0 + 7] + er_b[i0 + 7];
            uint4 pk;
            pk.x = (u32)f2bf(v0) | ((u32)f2bf(v1) << 16);
            pk.y = (u32)f2bf(v2) | ((u32)f2bf(v3) << 16);
            pk.z = (u32)f2bf(v4) | ((u32)f2bf(v5) << 16);
            pk.w = (u32)f2bf(v6) | ((u32)f2bf(v7) << 16);
            int ks = i0 ^ ((row & 7) << 3);
            *(uint4*)&Xs[row * 64 + ks] = pk;
        }
    }
    __syncthreads();

    int w = tid >> 6;
    int l = tid & 63;
    int l16 = l & 15, lq = l >> 4;

    bf16x8 xb[2][2];
    #pragma unroll
    for (int rt = 0; rt < 2; ++rt) {
        int row = w * 32 + rt * 16 + l16;
        #pragma unroll
        for (int kt = 0; kt < 2; ++kt) {
            int k0 = kt * 32 + lq * 8;
            int ks = k0 ^ ((row & 7) << 3);
            xb[rt][kt] = *(const bf16x8*)&Xs[row * 64 + ks];
        }
    }
    f32x4 acc[8][2];
    #pragma unroll
    for (int jt = 0; jt < 8; ++jt)
        #pragma unroll
        for (int rt = 0; rt < 2; ++rt)
            acc[jt][rt] = (f32x4){0.f, 0.f, 0.f, 0.f};

    #pragma unroll
    for (int jt = 0; jt < 8; ++jt) {
        int j = jt * 16 + l16;
        int ks0 = (lq * 8) ^ ((j & 7) << 3);
        int ks1 = (32 + lq * 8) ^ ((j & 7) << 3);
        bf16x8 a0 = *(const bf16x8*)&W1s[j * 64 + ks0];
        bf16x8 a1 = *(const bf16x8*)&W1s[j * 64 + ks1];
        #pragma unroll
        for (int rt = 0; rt < 2; ++rt) {
            acc[jt][rt] = __builtin_amdgcn_mfma_f32_16x16x32_bf16(a0, xb[rt][0], acc[jt][rt], 0, 0, 0);
            acc[jt][rt] = __builtin_amdgcn_mfma_f32_16x16x32_bf16(a1, xb[rt][1], acc[jt][rt], 0, 0, 0);
        }
    }

    float part0 = 0.f, part1 = 0.f;
    #pragma unroll
    for (int jt = 0; jt < 8; ++jt) {
        float4 wq = *(const float4*)&w2qs[jt * 16 + lq * 4];
        float4 bb = *(const float4*)&b1s[jt * 16 + lq * 4];
        part0 += fmaxf(acc[jt][0][0] + bb.x, 0.f) * wq.x;
        part0 += fmaxf(acc[jt][0][1] + bb.y, 0.f) * wq.y;
        part0 += fmaxf(acc[jt][0][2] + bb.z, 0.f) * wq.z;
        part0 += fmaxf(acc[jt][0][3] + bb.w, 0.f) * wq.w;
        part1 += fmaxf(acc[jt][1][0] + bb.x, 0.f) * wq.x;
        part1 += fmaxf(acc[jt][1][1] + bb.y, 0.f) * wq.y;
        part1 += fmaxf(acc[jt][1][2] + bb.z, 0.f) * wq.z;
        part1 += fmaxf(acc[jt][1][3] + bb.w, 0.f) * wq.w;
    }
    part0 += __shfl_xor(part0, 16); part0 += __shfl_xor(part0, 32);
    part1 += __shfl_xor(part1, 16); part1 += __shfl_xor(part1, 32);
    if (lq == 0) {
        float bq = b2q[bs];
        int n0 = half * 128 + w * 32;
        logits[(size_t)(b * N + n0 + l16) * S + s]      = part0 + bq;
        logits[(size_t)(b * N + n0 + 16 + l16) * S + s] = part1 + bq;
    }
}

// ============ K3b: v path — layer1 MFMA -> H(LDS) -> layer2 MFMA -> v_buf ===
__global__ __launch_bounds__(256) void vff_kernel(
    const float* __restrict__ iv,
    const float* __restrict__ s_p, const float* __restrict__ s_s,
    const float* __restrict__ er_w, const float* __restrict__ er_b,
    const u16* __restrict__ w1t, const float* __restrict__ mi_b1,
    const u16* __restrict__ w2t, const float* __restrict__ mi_b2,
    float* __restrict__ v_buf) {
    int blk = blockIdx.x;
    int half = blk & 1;
    int bs = blk >> 1;
    int b = bs / S;
    int tid = threadIdx.x;

    __shared__ u16 Xs[128 * 64];
    __shared__ u16 W1s[128 * 64];
    __shared__ u16 W2s[64 * 128];
    __shared__ u16 Hs[128 * 128];
    __shared__ float b1s[128];

    const uint4* w1g = (const uint4*)w1t;
    const uint4* w2g = (const uint4*)w2t;
    for (int c = tid; c < 1024; c += 256) {
        int j = c >> 3, k0 = (c & 7) * 8;
        int ks = k0 ^ ((j & 7) << 3);
        *(uint4*)&W1s[j * 64 + ks] = w1g[c];
        int dd = c >> 4, k2 = (c & 15) * 8;
        int ks2 = k2 ^ ((dd & 15) << 3);
        *(uint4*)&W2s[dd * 128 + ks2] = w2g[c];
    }
    if (tid < 128) b1s[tid] = mi_b1[tid];

    {
        float p0 = s_p[bs * 2 + 0], p1 = s_p[bs * 2 + 1];
        float ss0 = s_s[bs * 2 + 0], ss1 = s_s[bs * 2 + 1];
        int row = tid >> 1;
        int kh = (tid & 1) * 32;
        int n = half * 128 + row;
        float g0 = grid_coord(n >> 4), g1 = grid_coord(n & 15);
        float r0 = (g0 - p0) / ss0, r1 = (g1 - p1) / ss1;
        const float4* src4 = (const float4*)(iv + (size_t)(b * N + n) * D + kh);
        #pragma unroll
        for (int c2 = 0; c2 < 4; ++c2) {
            int i0 = kh + c2 * 8;
            float4 ta = src4[c2 * 2 + 0];
            float4 tb = src4[c2 * 2 + 1];
            float v0 = ta.x + r0 * er_w[i0 + 0] + r1 * er_w[D + i0 + 0] + er_b[i0 + 0];
            float v1 = ta.y + r0 * er_w[i0 + 1] + r1 * er_w[D + i0 + 1] + er_b[i0 + 1];
            float v2 = ta.z + r0 * er_w[i0 + 2] + r1 * er_w[D + i0 + 2] + er_b[i0 + 2];
            float v3 = ta.w + r0 * er_w[i0 + 3] + r1 * er_w[D + i0 + 3] + er_b[i0 + 3];
            float v4 = tb.x + r0 * er_w[i0 + 4] + r1 * er_w[D + i0 + 4] + er_b[i0 + 4];
            float v5 = tb.y + r0 * er_w[i0 + 5] + r1 * er_w[D + i0 + 5] + er_b[i0 + 5];
            float v6 = tb.z + r0 * er_w[i0 + 6] + r1 * er_w[D + i0 + 6] + er_b[i0 + 6];
            float v7 = tb.w + r0 * er_w[i0 + 7] + r1 * er_w[D + i0 + 7] + er_b[i0 + 7];
            uint4 pk;
            pk.x = (u32)f2bf(v0) | ((u32)f2bf(v1) << 16);
            pk.y = (u32)f2bf(v2) | ((u32)f2bf(v3) << 16);
            pk.z = (u32)f2bf(v4) | ((u32)f2bf(v5) << 16);
            pk.w = (u32)f2bf(v6) | ((u32)f2bf(v7) << 16);
            int ks = i0 ^ ((row & 7) << 3);
            *(uint4*)&Xs[row * 64 + ks] = pk;
        }
    }
    __syncthreads();

    int w = tid >> 6;
    int l = tid & 63;
    int l16 = l & 15, lq = l >> 4;

    bf16x8 xb[2][2];
    #pragma unroll
    for (int rt = 0; rt < 2; ++rt) {
        int row = w * 32 + rt * 16 + l16;
        #pragma unroll
        for (int kt = 0; kt < 2; ++kt) {
            int k0 = kt * 32 + lq * 8;
            int ks = k0 ^ ((row & 7) << 3);
            xb[rt][kt] = *(const bf16x8*)&Xs[row * 64 + ks];
        }
    }
    f32x4 acc[8][2];
    #pragma unroll
    for (int jt = 0; jt < 8; ++jt)
        #pragma unroll
        for (int rt = 0; rt < 2; ++rt)
            acc[jt][rt] = (f32x4){0.f, 0.f, 0.f, 0.f};

    #pragma unroll
    for (int jt = 0; jt < 8; ++jt) {
        int j = jt * 16 + l16;
        int ks0 = (lq * 8) ^ ((j & 7) << 3);
        int ks1 = (32 + lq * 8) ^ ((j & 7) << 3);
        bf16x8 a0 = *(const bf16x8*)&W1s[j * 64 + ks0];
        bf16x8 a1 = *(const bf16x8*)&W1s[j * 64 + ks1];
        #pragma unroll
        for (int rt = 0; rt < 2; ++rt) {
            acc[jt][rt] = __builtin_amdgcn_mfma_f32_16x16x32_bf16(a0, xb[rt][0], acc[jt][rt], 0, 0, 0);
            acc[jt][rt] = __builtin_amdgcn_mfma_f32_16x16x32_bf16(a1, xb[rt][1], acc[jt][rt], 0, 0, 0);
        }
    }

    #pragma unroll
    for (int jt = 0; jt < 8; ++jt) {
        float4 bb = *(const float4*)&b1s[jt * 16 + lq * 4];
        #pragma unroll
        for (int rt = 0; rt < 2; ++rt) {
            int row = w * 32 + rt * 16 + l16;
            float h0 = fmaxf(acc[jt][rt][0] + bb.x, 0.f);
            float h1 = fmaxf(acc[jt][rt][1] + bb.y, 0.f);
            float h2 = fmaxf(acc[jt][rt][2] + bb.z, 0.f);
            float h3 = fmaxf(acc[jt][rt][3] + bb.w, 0.f);
            u32 p0 = (u32)f2bf(h0) | ((u32)f2bf(h1) << 16);
            u32 p1 = (u32)f2bf(h2) | ((u32)f2bf(h3) << 16);
            int j0 = jt * 16 + lq * 4;
            int js = j0 ^ ((row & 15) << 3);
            *(uint2*)&Hs[row * 128 + js] = make_uint2(p0, p1);
        }
    }
    __syncthreads();

    f32x4 acc2[2][4];
    #pragma unroll
    for (int mt = 0; mt < 2; ++mt)
        #pragma unroll
        for (int nt = 0; nt < 4; ++nt)
            acc2[mt][nt] = (f32x4){0.f, 0.f, 0.f, 0.f};

    #pragma unroll
    for (int kt = 0; kt < 4; ++kt) {
        bf16x8 af[2], bw[4];
        #pragma unroll
        for (int mt = 0; mt < 2; ++mt) {
            int row = w * 32 + mt * 16 + l16;
            int js = (kt * 32 + lq * 8) ^ ((row & 15) << 3);
            af[mt] = *(const bf16x8*)&Hs[row * 128 + js];
        }
        #pragma unroll
        for (int nt = 0; nt < 4; ++nt) {
            int dd = nt * 16 + l16;
            int ks = (kt * 32 + lq * 8) ^ ((dd & 15) << 3);
            bw[nt] = *(const bf16x8*)&W2s[dd * 128 + ks];
        }
        #pragma unroll
        for (int mt = 0; mt < 2; ++mt)
            #pragma unroll
            for (int nt = 0; nt < 4; ++nt)
                acc2[mt][nt] = __builtin_amdgcn_mfma_f32_16x16x32_bf16(af[mt], bw[nt], acc2[mt][nt], 0, 0, 0);
    }

    #pragma unroll
    for (int nt = 0; nt < 4; ++nt) {
        float b2v = mi_b2[nt * 16 + l16];
        #pragma unroll
        for (int mt = 0; mt < 2; ++mt) {
            #pragma unroll
            for (int r = 0; r < 4; ++r) {
                int n = half * 128 + w * 32 + mt * 16 + lq * 4 + r;
                v_buf[((size_t)bs * N + n) * D + nt * 16 + l16] = acc2[mt][nt][r] + b2v;
            }
        }
    }
}

// ---------------- K4: softmax over slots, renorm over n, calcSP -------------
__global__ __launch_bounds__(256) void attn_kernel(
    const float* __restrict__ logits,
    float* __restrict__ attn_out, float* __restrict__ s_p, float* __restrict__ s_s) {
    int b = blockIdx.x;
    int n = threadIdx.x;
    float a[S];
    const float* lr = logits + (b * N + n) * S;
    float m = -1e30f;
    #pragma unroll
    for (int s = 0; s < S; ++s) { a[s] = lr[s]; m = fmaxf(m, a[s]); }
    float sum = 0.f;
    #pragma unroll
    for (int s = 0; s < S; ++s) { a[s] = expf(a[s] - m); sum += a[s]; }
    float inv = 1.0f / sum;
    #pragma unroll
    for (int s = 0; s < S; ++s) a[s] = a[s] * inv + 1e-8f;

    __shared__ float cs[S];
    __shared__ float wp_l[S][2];
    __shared__ float ws_l[S][2];
    if (n < S) {
        cs[n] = 0.f;
        wp_l[n][0] = 0.f; wp_l[n][1] = 0.f;
        ws_l[n][0] = 0.f; ws_l[n][1] = 0.f;
    }
    __syncthreads();
    #pragma unroll
    for (int s = 0; s < S; ++s) {
        float v = a[s];
        #pragma unroll
        for (int off = 32; off > 0; off >>= 1) v += __shfl_xor(v, off);
        if ((n & 63) == 0) atomicAdd(&cs[s], v);
    }
    __syncthreads();
    #pragma unroll
    for (int s = 0; s < S; ++s) a[s] /= cs[s];
    float* ao = attn_out + (b * N + n) * S;
    #pragma unroll
    for (int s = 0; s < S; ++s) ao[s] = a[s];

    float g0 = grid_coord(n >> 4), g1 = grid_coord(n & 15);
    #pragma unroll
    for (int s = 0; s < S; ++s) {
        float c0 = a[s] * g0, c1 = a[s] * g1;
        #pragma unroll
        for (int off = 32; off > 0; off >>= 1) {
            c0 += __shfl_xor(c0, off); c1 += __shfl_xor(c1, off);
        }
        if ((n & 63) == 0) { atomicAdd(&wp_l[s][0], c0); atomicAdd(&wp_l[s][1], c1); }
    }
    __syncthreads();
    #pragma unroll
    for (int s = 0; s < S; ++s) {
        float aw = a[s] + 1e-11f;
        float d0 = g0 - wp_l[s][0], d1 = g1 - wp_l[s][1];
        float c0 = d0 * d0 * aw, c1 = d1 * d1 * aw;
        #pragma unroll
        for (int off = 32; off > 0; off >>= 1) {
            c0 += __shfl_xor(c0, off); c1 += __shfl_xor(c1, off);
        }
        if ((n & 63) == 0) { atomicAdd(&ws_l[s][0], c0); atomicAdd(&ws_l[s][1], c1); }
    }
    __syncthreads();
    if (n < S) {
        s_p[(b * S + n) * 2 + 0] = wp_l[n][0];
        s_p[(b * S + n) * 2 + 1] = wp_l[n][1];
        float w0 = sqrtf(ws_l[n][0]), w1 = sqrtf(ws_l[n][1]);
        s_s[(b * S + n) * 2 + 0] = fminf(fmaxf(w0, 0.001f), 5.0f);
        s_s[(b * S + n) * 2 + 1] = fminf(fmaxf(w1, 0.001f), 5.0f);
    }
}

// ---------------- K5: updates = attn^T v ; GRU ; residual MLP ---------------
__global__ __launch_bounds__(256) void update_kernel(
    const float* __restrict__ attn, const float* __restrict__ v_buf,
    const float* __restrict__ gru_k, const float* __restrict__ gru_rk,
    const float* __restrict__ gru_b,
    const float* __restrict__ nm_g, const float* __restrict__ nm_b,
    const float* __restrict__ mlp_w1, const float* __restrict__ mlp_b1,
    const float* __restrict__ mlp_w2, const float* __restrict__ mlp_b2,
    float* __restrict__ slots) {
    int bs = blockIdx.x;
    int b = bs / S, s = bs % S;
    int tid = threadIdx.x;
    int wv = tid >> 6, d = tid & 63;
    const float* vrow = v_buf + (size_t)bs * N * D;
    float u = 0.f;
    for (int n = wv; n < N; n += 4) {
        float a = attn[(b * N + n) * S + s];
        u += a * vrow[n * D + d];
    }
    __shared__ float part[4][64];
    __shared__ float ul[D], hl[D], xl[D], hb[128];
    part[wv][d] = u;
    __syncthreads();
    float sn = 0.f;
    if (tid < 64) {
        float uu = part[0][d] + part[1][d] + part[2][d] + part[3][d];
        ul[d] = uu;
        hl[d] = slots[bs * D + d];
    }
    __syncthreads();
    if (tid < 64) {
        float h = hl[d];
        float xz = gru_b[d], xr = gru_b[64 + d], xh = gru_b[128 + d];
        float hz = gru_b[192 + d], hr = gru_b[256 + d], hh = gru_b[320 + d];
        for (int i = 0; i < D; ++i) {
            float ui = ul[i], hi = hl[i];
            xz += ui * gru_k[i * 192 + d];
            xr += ui * gru_k[i * 192 + 64 + d];
            xh += ui * gru_k[i * 192 + 128 + d];
            hz += hi * gru_rk[i * 192 + d];
            hr += hi * gru_rk[i * 192 + 64 + d];
            hh += hi * gru_rk[i * 192 + 128 + d];
        }
        float z = 1.f / (1.f + expf(-(xz + hz)));
        float r = 1.f / (1.f + expf(-(xr + hr)));
        float hc = tanhf(xh + r * hh);
        sn = z * h + (1.f - z) * hc;
        float sum = sn;
        #pragma unroll
        for (int off = 32; off > 0; off >>= 1) sum += __shfl_xor(sum, off);
        float mm = sum * (1.0f / 64.0f);
        float dx = sn - mm;
        float vs = dx * dx;
        #pragma unroll
        for (int off = 32; off > 0; off >>= 1) vs += __shfl_xor(vs, off);
        float var = vs * (1.0f / 64.0f);
        xl[d] = dx * rsqrtf(var + LN_EPS) * nm_g[d] + nm_b[d];
    }
    __syncthreads();
    if (tid < 128) {
        int j = tid;
        float h1 = mlp_b1[j];
        #pragma unroll 8
        for (int i = 0; i < D; ++i) h1 += xl[i] * mlp_w1[i * 128 + j];
        hb[j] = fmaxf(h1, 0.f);
    }
    __syncthreads();
    if (tid < 64) {
        float o = mlp_b2[d];
        #pragma unroll 8
        for (int j = 0; j < 128; ++j) o += hb[j] * mlp_w2[j * D + d];
        slots[bs * D + d] = sn + o;
    }
}

// ---------------- K6: copy slots, s_p, s_s to output ------------------------
__global__ void copyout_kernel(
    const float* __restrict__ slots, const float* __restrict__ s_p,
    const float* __restrict__ s_s, float* __restrict__ out) {
    int idx = blockIdx.x * blockDim.x + threadIdx.x;
    if (idx < B * S * D) out[idx] = slots[idx];
    else if (idx < B * S * D + B * S * 2) out[idx] = s_p[idx - B * S * D];
    else if (idx < B * S * D + 2 * B * S * 2) out[idx] = s_s[idx - B * S * D - B * S * 2];
}

extern "C" void kernel_launch(void* const* d_in, const int* in_sizes, int n_in,
                              void* d_out, int out_size, void* d_ws, size_t ws_size,
                              hipStream_t stream) {
    const float* inputs  = (const float*)d_in[0];
    const float* s_p0    = (const float*)d_in[1];
    const float* s_s0    = (const float*)d_in[2];
    const float* slots_mu= (const float*)d_in[3];
    const float* es_w1   = (const float*)d_in[4];
    const float* es_b1   = (const float*)d_in[5];
    const float* es_w2   = (const float*)d_in[6];
    const float* es_b2   = (const float*)d_in[7];
    const float* er_w    = (const float*)d_in[8];
    const float* er_b    = (const float*)d_in[9];
    const float* pk_w    = (const float*)d_in[10];
    const float* pk_b    = (const float*)d_in[11];
    const float* pv_w    = (const float*)d_in[12];
    const float* pv_b    = (const float*)d_in[13];
    const float* pq_w    = (const float*)d_in[14];
    const float* pq_b    = (const float*)d_in[15];
    const float* mi_w1   = (const float*)d_in[16];
    const float* mi_b1   = (const float*)d_in[17];
    const float* mi_w2   = (const float*)d_in[18];
    const float* mi_b2   = (const float*)d_in[19];
    const float* ns_g    = (const float*)d_in[20];
    const float* ns_b    = (const float*)d_in[21];
    const float* nm_g    = (const float*)d_in[22];
    const float* nm_b    = (const float*)d_in[23];
    const float* gru_k   = (const float*)d_in[24];
    const float* gru_rk  = (const float*)d_in[25];
    const float* gru_b   = (const float*)d_in[26];
    const float* mlp_w1  = (const float*)d_in[27];
    const float* mlp_b1  = (const float*)d_in[28];
    const float* mlp_w2  = (const float*)d_in[29];
    const float* mlp_b2  = (const float*)d_in[30];

    float* ws    = (float*)d_ws;
    float* pos   = ws;                      // 131072 floats; reused after projkv:
    u16*   w1t   = (u16*)pos;               //   8192 u16
    u16*   w2t   = (u16*)pos + 8192;        //   8192 u16
    float* w2qb  = pos + 8192;              //   45056 floats
    float* b2qb  = pos + 53248;             //   352 floats
    float* ik    = pos + 131072;            // 524288
    float* iv    = ik + 524288;             // 524288
    float* vb    = iv + 524288;             // 5767168
    float* lgts  = vb + 5767168;            // 90112
    float* slots = lgts + 90112;            // 22528
    float* sp    = slots + 22528;           // 704
    float* ssg   = sp + 704;                // 704
    // wkv split-bf16 weights overlay the v_buf region (free until first vff)
    u16*   wkvh  = (u16*)vb;                // 65536 u16
    u16*   wkvl  = (u16*)vb + 65536;        // 65536 u16

    float* out      = (float*)d_out;
    float* attn_out = out + B * S * D + 2 * B * S * 2;

    pos_kernel<<<256, 128, 0, stream>>>(es_w1, es_b1, es_w2, es_b2, pos);
    init_kernel<<<88, 256, 0, stream>>>(slots_mu, s_p0, s_s0, slots, sp, ssg);
    wprep_kernel<<<320, 256, 0, stream>>>(mi_w1, mi_w2, pk_w, pv_w, w1t, w2t, wkvh, wkvl);
    projkv_kernel<<<512, 64, 0, stream>>>(inputs, pos, wkvh, wkvl, pk_b, pv_b, ik, iv);

    for (int ind = 0; ind < 4; ++ind) {
        qw2q_kernel<<<352, 128, 0, stream>>>(slots, ns_g, ns_b, pq_w, pq_b,
                                             mi_w2, mi_b2, w2qb, b2qb);
        klogits_kernel<<<704, 256, 0, stream>>>(ik, sp, ssg, er_w, er_b,
                                                w1t, mi_b1, w2qb, b2qb, lgts);
        vff_kernel<<<704, 256, 0, stream>>>(iv, sp, ssg, er_w, er_b,
                                            w1t, mi_b1, w2t, mi_b2, vb);
        attn_kernel<<<32, 256, 0, stream>>>(lgts, attn_out, sp, ssg);
        if (ind < 3)
            update_kernel<<<352, 256, 0, stream>>>(attn_out, vb, gru_k, gru_rk, gru_b,
                                                   nm_g, nm_b, mlp_w1, mlp_b1,
                                                   mlp_w2, mlp_b2, slots);
    }
    copyout_kernel<<<94, 256, 0, stream>>>(slots, sp, ssg, out);
}

// Round 4
// 299.463 us; speedup vs baseline: 4.7556x; 1.2113x over previous
//
#include <hip/hip_runtime.h>
#include <cmath>

#define B 32
#define S 11
#define R 16
#define D 64
#define C 512
#define N 256   // R*R
#define LN_EPS 1e-3f

typedef unsigned short u16;
typedef unsigned int   u32;

using bf16x8 = __attribute__((ext_vector_type(8))) short;
using f32x4  = __attribute__((ext_vector_type(4))) float;

__device__ __forceinline__ float grid_coord(int i) {
    return -1.0f + (2.0f / 15.0f) * (float)i;
}

__device__ __forceinline__ u16 f2bf(float x) {
    union { float f; u32 u; } c; c.f = x;
    u32 r = c.u + 0x7fffu + ((c.u >> 16) & 1u);   // RNE
    return (u16)(r >> 16);
}

// ---------------- K0: positional embedding pos[n, c] (once) ----------------
__global__ __launch_bounds__(128) void pos_kernel(
    const float* __restrict__ es_w1, const float* __restrict__ es_b1,
    const float* __restrict__ es_w2, const float* __restrict__ es_b2,
    float* __restrict__ pos) {
    int n = blockIdx.x;       // 0..255
    int j = threadIdx.x;      // 0..127
    float g0 = grid_coord(n >> 4), g1 = grid_coord(n & 15);
    __shared__ float h[128];
    float hj = es_b1[j] + g0 * es_w1[j] + g1 * es_w1[128 + j];
    h[j] = fmaxf(hj, 0.0f);
    __syncthreads();
    for (int c0 = 0; c0 < C; c0 += 128) {
        int c = c0 + j;
        float acc = es_b2[c];
        #pragma unroll 16
        for (int jj = 0; jj < 128; ++jj) acc += h[jj] * es_w2[jj * C + c];
        pos[n * C + c] = acc;
    }
}

// ---------------- K_init ----------------------------------------------------
__global__ void init_kernel(
    const float* __restrict__ slots_mu, const float* __restrict__ s_p0,
    const float* __restrict__ s_s0,
    float* __restrict__ slots, float* __restrict__ s_p, float* __restrict__ s_s) {
    int idx = blockIdx.x * blockDim.x + threadIdx.x;
    if (idx < B * S * D) slots[idx] = slots_mu[idx % (S * D)];
    if (idx < B * S * 2) { s_p[idx] = s_p0[idx]; s_s[idx] = s_s0[idx]; }
}

// ---------------- K_wprep: all weight prep (once) ---------------------------
// WkT[j][c] = bf16(sum_k pk_w[c][k] mi_w1[k][j])   [128][512]
// WvT[j][c] = same with pv_w
// w2t[d][j] = bf16(mi_w2[j][d])                     [64][128]
// ewp: [0:128)=ew0, [128:256)=ew1, [256:384)=bbk, [384:512)=bbv (fp32)
__global__ __launch_bounds__(256) void wprep_kernel(
    const float* __restrict__ mi_w1, const float* __restrict__ mi_b1,
    const float* __restrict__ mi_w2,
    const float* __restrict__ pk_w, const float* __restrict__ pk_b,
    const float* __restrict__ pv_w, const float* __restrict__ pv_b,
    const float* __restrict__ er_w, const float* __restrict__ er_b,
    u16* __restrict__ wkT, u16* __restrict__ wvT, u16* __restrict__ w2t,
    float* __restrict__ ewp) {
    int idx = blockIdx.x * 256 + threadIdx.x;
    if (idx < 131072) {
        int mat = idx >> 16;           // 0=k, 1=v
        int i = idx & 65535;
        int c = i >> 7, j = i & 127;
        const float* pw = mat ? pv_w : pk_w;
        float acc = 0.f;
        #pragma unroll 8
        for (int k = 0; k < 64; ++k) acc += pw[c * 64 + k] * mi_w1[k * 128 + j];
        u16* dst = mat ? wvT : wkT;
        dst[j * 512 + c] = f2bf(acc);
    } else if (idx < 139264) {
        int i = idx - 131072;          // 0..8191
        int dd = i >> 7, j = i & 127;
        w2t[i] = f2bf(mi_w2[j * 64 + dd]);
    } else if (idx < 139776) {
        int i = idx - 139264;          // 0..511
        int t = i >> 7, j = i & 127;
        float acc = 0.f;
        if (t == 0) {
            for (int k = 0; k < 64; ++k) acc += er_w[k] * mi_w1[k * 128 + j];
        } else if (t == 1) {
            for (int k = 0; k < 64; ++k) acc += er_w[64 + k] * mi_w1[k * 128 + j];
        } else if (t == 2) {
            for (int k = 0; k < 64; ++k) acc += (pk_b[k] + er_b[k]) * mi_w1[k * 128 + j];
            acc += mi_b1[j];
        } else {
            for (int k = 0; k < 64; ++k) acc += (pv_b[k] + er_b[k]) * mi_w1[k * 128 + j];
            acc += mi_b1[j];
        }
        ewp[i] = acc;
    }
}

// ---------------- K1: G = (inputs+pos) @ Wk1 / Wv1 via MFMA (once) ----------
// kv=0: GkT[b][j][n] ; kv=1: Gv[b][n][j]
__global__ __launch_bounds__(256) void xw1_kernel(
    const float* __restrict__ inputs, const float* __restrict__ pos,
    const u16* __restrict__ WT,      // wkT base; wvT at +65536
    float* __restrict__ GkT, float* __restrict__ Gv) {
    int blk = blockIdx.x;            // 256
    int kv = blk & 1;
    int tile = blk >> 1;             // 0..127, 64 rows each
    int t = threadIdx.x;
    int w = t >> 6, l = t & 63;
    int l16 = l & 15, lq = l >> 4;
    int row0 = tile * 64 + w * 16;   // global row in [0, 8192)
    const u16* Wm = WT + (size_t)kv * 65536;

    int xrow = row0 + l16;
    const float* xi = inputs + (size_t)xrow * C;
    const float* xp = pos + (size_t)(xrow & (N - 1)) * C;

    f32x4 acc[8];
    #pragma unroll
    for (int jt = 0; jt < 8; ++jt) acc[jt] = (f32x4){0.f, 0.f, 0.f, 0.f};

    for (int kt = 0; kt < 16; ++kt) {
        int c0 = kt * 32 + lq * 8;
        float4 a0 = *(const float4*)(xi + c0);
        float4 a1 = *(const float4*)(xi + c0 + 4);
        float4 p0 = *(const float4*)(xp + c0);
        float4 p1 = *(const float4*)(xp + c0 + 4);
        union { bf16x8 v; u16 s[8]; } xf;
        xf.s[0] = f2bf(a0.x + p0.x); xf.s[1] = f2bf(a0.y + p0.y);
        xf.s[2] = f2bf(a0.z + p0.z); xf.s[3] = f2bf(a0.w + p0.w);
        xf.s[4] = f2bf(a1.x + p1.x); xf.s[5] = f2bf(a1.y + p1.y);
        xf.s[6] = f2bf(a1.z + p1.z); xf.s[7] = f2bf(a1.w + p1.w);
        #pragma unroll
        for (int jt = 0; jt < 8; ++jt) {
            bf16x8 wf = *(const bf16x8*)(Wm + (size_t)(jt * 16 + l16) * 512 + c0);
            if (kv == 0)
                acc[jt] = __builtin_amdgcn_mfma_f32_16x16x32_bf16(wf, xf.v, acc[jt], 0, 0, 0);
            else
                acc[jt] = __builtin_amdgcn_mfma_f32_16x16x32_bf16(xf.v, wf, acc[jt], 0, 0, 0);
        }
    }
    int b = row0 >> 8;
    int n0 = row0 & (N - 1);
    if (kv == 0) {
        #pragma unroll
        for (int jt = 0; jt < 8; ++jt)
            #pragma unroll
            for (int r = 0; r < 4; ++r)
                GkT[((size_t)b * 128 + jt * 16 + lq * 4 + r) * 256 + n0 + l16] = acc[jt][r];
    } else {
        #pragma unroll
        for (int jt = 0; jt < 8; ++jt)
            #pragma unroll
            for (int r = 0; r < 4; ++r)
                Gv[((size_t)b * 256 + n0 + lq * 4 + r) * 128 + jt * 16 + l16] = acc[jt][r];
    }
}

// ---------------- K2: initial q -> w2q, b2q (only before iter 0) ------------
__global__ __launch_bounds__(128) void qw2q_kernel(
    const float* __restrict__ slots,
    const float* __restrict__ ns_g, const float* __restrict__ ns_b,
    const float* __restrict__ pq_w, const float* __restrict__ pq_b,
    const float* __restrict__ mi_w2, const float* __restrict__ mi_b2,
    float* __restrict__ w2q, float* __restrict__ b2q) {
    int bs = blockIdx.x;
    int t = threadIdx.x;
    __shared__ float xlds[64], qs[64];
    if (t < 64) {
        float x = slots[bs * D + t];
        float sum = x;
        #pragma unroll
        for (int off = 32; off > 0; off >>= 1) sum += __shfl_xor(sum, off);
        float m = sum * (1.0f / 64.0f);
        float dx = x - m;
        float vs = dx * dx;
        #pragma unroll
        for (int off = 32; off > 0; off >>= 1) vs += __shfl_xor(vs, off);
        float var = vs * (1.0f / 64.0f);
        xlds[t] = dx * rsqrtf(var + LN_EPS) * ns_g[t] + ns_b[t];
    }
    __syncthreads();
    if (t < 64) {
        float acc = pq_b[t];
        #pragma unroll 8
        for (int i = 0; i < 64; ++i) acc += xlds[i] * pq_w[i * D + t];
        qs[t] = acc * 0.125f;
    }
    __syncthreads();
    {
        float s = 0.f;
        #pragma unroll 8
        for (int dd = 0; dd < 64; ++dd) s += mi_w2[t * 64 + dd] * qs[dd];
        w2q[bs * 128 + t] = s;
    }
    if (t < 64) {
        float v = mi_b2[t] * qs[t];
        #pragma unroll
        for (int off = 32; off > 0; off >>= 1) v += __shfl_xor(v, off);
        if (t == 0) b2q[bs] = v;
    }
}

// ============ K3a: k path — rank-2 layer1 + dot with w2q -> logits ==========
__global__ __launch_bounds__(128) void klogits_kernel(
    const float* __restrict__ GkT,
    const float* __restrict__ s_p, const float* __restrict__ s_s,
    const float* __restrict__ ewp,
    const float* __restrict__ w2q, const float* __restrict__ b2q,
    float* __restrict__ logits) {
    int orig = blockIdx.x;                       // 704 = 8*88
    int blk = (orig & 7) * 88 + (orig >> 3);     // XCD-chunked swizzle
    int half = blk & 1;
    int bs = blk >> 1;
    int b = bs / S, s = bs - b * S;
    int t = threadIdx.x;
    int n = half * 128 + t;

    __shared__ float e0s[128], e1s[128], bbs[128], wqs[128];
    e0s[t] = ewp[t]; e1s[t] = ewp[128 + t];
    bbs[t] = ewp[256 + t]; wqs[t] = w2q[bs * 128 + t];
    __syncthreads();

    float p0 = s_p[bs * 2 + 0], p1 = s_p[bs * 2 + 1];
    float ss0 = s_s[bs * 2 + 0], ss1 = s_s[bs * 2 + 1];
    float g0 = grid_coord(n >> 4), g1 = grid_coord(n & 15);
    float r0 = (g0 - p0) / ss0, r1 = (g1 - p1) / ss1;

    const float* Gb = GkT + (size_t)b * 128 * 256 + n;
    float acc = 0.f;
    #pragma unroll 8
    for (int j = 0; j < 128; ++j) {
        float h = Gb[j * 256] + r0 * e0s[j] + r1 * e1s[j] + bbs[j];
        acc += fmaxf(h, 0.f) * wqs[j];
    }
    logits[(size_t)(b * N + n) * S + s] = acc + b2q[bs];
}

// ============ K3b: v path — rank-2 layer1 -> H(LDS) -> layer2 MFMA ==========
__global__ __launch_bounds__(256) void vff_kernel(
    const float* __restrict__ Gv,
    const float* __restrict__ s_p, const float* __restrict__ s_s,
    const float* __restrict__ ewp,
    const u16* __restrict__ w2t, const float* __restrict__ mi_b2,
    float* __restrict__ v_buf) {
    int orig = blockIdx.x;
    int blk = (orig & 7) * 88 + (orig >> 3);
    int half = blk & 1;
    int bs = blk >> 1;
    int b = bs / S;
    int t = threadIdx.x;

    __shared__ u16 Hs[128 * 128];
    __shared__ float e0s[128], e1s[128], bbs[128];
    if (t < 128) { e0s[t] = ewp[t]; e1s[t] = ewp[128 + t]; bbs[t] = ewp[384 + t]; }
    __syncthreads();

    float p0 = s_p[bs * 2 + 0], p1 = s_p[bs * 2 + 1];
    float ss0 = s_s[bs * 2 + 0], ss1 = s_s[bs * 2 + 1];
    {
        int row = t >> 1;
        int jh = (t & 1) * 64;
        int n = half * 128 + row;
        float g0 = grid_coord(n >> 4), g1 = grid_coord(n & 15);
        float r0 = (g0 - p0) / ss0, r1 = (g1 - p1) / ss1;
        const float* Gr = Gv + ((size_t)b * 256 + n) * 128 + jh;
        #pragma unroll
        for (int g = 0; g < 16; ++g) {
            float4 gv = *(const float4*)(Gr + g * 4);
            int j0 = jh + g * 4;
            float h0 = fmaxf(gv.x + r0 * e0s[j0 + 0] + r1 * e1s[j0 + 0] + bbs[j0 + 0], 0.f);
            float h1 = fmaxf(gv.y + r0 * e0s[j0 + 1] + r1 * e1s[j0 + 1] + bbs[j0 + 1], 0.f);
            float h2 = fmaxf(gv.z + r0 * e0s[j0 + 2] + r1 * e1s[j0 + 2] + bbs[j0 + 2], 0.f);
            float h3 = fmaxf(gv.w + r0 * e0s[j0 + 3] + r1 * e1s[j0 + 3] + bbs[j0 + 3], 0.f);
            u32 lo = (u32)f2bf(h0) | ((u32)f2bf(h1) << 16);
            u32 hi = (u32)f2bf(h2) | ((u32)f2bf(h3) << 16);
            int js = j0 ^ ((row & 15) << 3);
            *(uint2*)&Hs[row * 128 + js] = make_uint2(lo, hi);
        }
    }
    __syncthreads();

    int w = t >> 6;
    int l = t & 63;
    int l16 = l & 15, lq = l >> 4;

    f32x4 acc2[2][4];
    #pragma unroll
    for (int mt = 0; mt < 2; ++mt)
        #pragma unroll
        for (int nt = 0; nt < 4; ++nt)
            acc2[mt][nt] = (f32x4){0.f, 0.f, 0.f, 0.f};

    #pragma unroll
    for (int kt = 0; kt < 4; ++kt) {
        bf16x8 af[2], bw[4];
        #pragma unroll
        for (int mt = 0; mt < 2; ++mt) {
            int row = w * 32 + mt * 16 + l16;
            int js = (kt * 32 + lq * 8) ^ ((row & 15) << 3);
            af[mt] = *(const bf16x8*)&Hs[row * 128 + js];
        }
        #pragma unroll
        for (int nt = 0; nt < 4; ++nt) {
            int dd = nt * 16 + l16;
            bw[nt] = *(const bf16x8*)(w2t + dd * 128 + kt * 32 + lq * 8);
        }
        #pragma unroll
        for (int mt = 0; mt < 2; ++mt)
            #pragma unroll
            for (int nt = 0; nt < 4; ++nt)
                acc2[mt][nt] = __builtin_amdgcn_mfma_f32_16x16x32_bf16(af[mt], bw[nt], acc2[mt][nt], 0, 0, 0);
    }

    #pragma unroll
    for (int nt = 0; nt < 4; ++nt) {
        float b2v = mi_b2[nt * 16 + l16];
        #pragma unroll
        for (int mt = 0; mt < 2; ++mt) {
            #pragma unroll
            for (int r = 0; r < 4; ++r) {
                int n = half * 128 + w * 32 + mt * 16 + lq * 4 + r;
                v_buf[((size_t)bs * N + n) * D + nt * 16 + l16] = acc2[mt][nt][r] + b2v;
            }
        }
    }
}

// ---------------- K4: softmax over slots, renorm over n, calcSP -------------
__global__ __launch_bounds__(256) void attn_kernel(
    const float* __restrict__ logits,
    float* __restrict__ attn_out,
    float* __restrict__ s_p, float* __restrict__ s_s,
    float* __restrict__ osp, float* __restrict__ oss) {
    int b = blockIdx.x;
    int n = threadIdx.x;
    int w = n >> 6, l = n & 63;
    float a[S];
    const float* lr = logits + (size_t)(b * N + n) * S;
    float m = -1e30f;
    #pragma unroll
    for (int s = 0; s < S; ++s) { a[s] = lr[s]; m = fmaxf(m, a[s]); }
    float sum = 0.f;
    #pragma unroll
    for (int s = 0; s < S; ++s) { a[s] = expf(a[s] - m); sum += a[s]; }
    float inv = 1.0f / sum;
    #pragma unroll
    for (int s = 0; s < S; ++s) a[s] = a[s] * inv + 1e-8f;

    __shared__ float As[S][N];
    __shared__ float cs[S];
    #pragma unroll
    for (int s = 0; s < S; ++s) As[s][n] = a[s];
    __syncthreads();

    for (int s = w; s < S; s += 4) {
        float sa = 0.f, s0 = 0.f, s1 = 0.f;
        #pragma unroll
        for (int i = 0; i < 4; ++i) {
            int nn = l + 64 * i;
            float av = As[s][nn];
            float g0 = grid_coord(nn >> 4), g1 = grid_coord(nn & 15);
            sa += av; s0 += av * g0; s1 += av * g1;
        }
        #pragma unroll
        for (int off = 32; off > 0; off >>= 1) {
            sa += __shfl_xor(sa, off);
            s0 += __shfl_xor(s0, off);
            s1 += __shfl_xor(s1, off);
        }
        float wp0 = s0 / sa, wp1 = s1 / sa;
        if (l == 0) cs[s] = sa;
        float inv_sa = 1.0f / sa;
        float t0 = 0.f, t1 = 0.f;
        #pragma unroll
        for (int i = 0; i < 4; ++i) {
            int nn = l + 64 * i;
            float av = As[s][nn] * inv_sa + 1e-11f;
            float g0 = grid_coord(nn >> 4), g1 = grid_coord(nn & 15);
            float d0 = g0 - wp0, d1 = g1 - wp1;
            t0 += d0 * d0 * av; t1 += d1 * d1 * av;
        }
        #pragma unroll
        for (int off = 32; off > 0; off >>= 1) {
            t0 += __shfl_xor(t0, off);
            t1 += __shfl_xor(t1, off);
        }
        if (l == 0) {
            int i = (b * S + s) * 2;
            float v0 = fminf(fmaxf(sqrtf(t0), 0.001f), 5.0f);
            float v1 = fminf(fmaxf(sqrtf(t1), 0.001f), 5.0f);
            s_p[i] = wp0; s_p[i + 1] = wp1;
            osp[i] = wp0; osp[i + 1] = wp1;
            s_s[i] = v0; s_s[i + 1] = v1;
            oss[i] = v0; oss[i + 1] = v1;
        }
    }
    __syncthreads();
    float* ao = attn_out + (size_t)(b * N + n) * S;
    #pragma unroll
    for (int s = 0; s < S; ++s) ao[s] = a[s] / cs[s];
}

// ---------------- K5: updates -> GRU -> MLP -> slots; fused next-iter q -----
__global__ __launch_bounds__(256) void update_kernel(
    const float* __restrict__ attn, const float* __restrict__ v_buf,
    const float* __restrict__ gru_k, const float* __restrict__ gru_rk,
    const float* __restrict__ gru_b,
    const float* __restrict__ nm_g, const float* __restrict__ nm_b,
    const float* __restrict__ mlp_w1, const float* __restrict__ mlp_b1,
    const float* __restrict__ mlp_w2, const float* __restrict__ mlp_b2,
    const float* __restrict__ ns_g, const float* __restrict__ ns_b,
    const float* __restrict__ pq_w, const float* __restrict__ pq_b,
    const float* __restrict__ mi_w2, const float* __restrict__ mi_b2,
    float* __restrict__ slots, float* __restrict__ out_slots,
    float* __restrict__ w2q, float* __restrict__ b2q) {
    int bs = blockIdx.x;
    int b = bs / S, s = bs - b * S;
    int tid = threadIdx.x;
    int wv = tid >> 6, d = tid & 63;
    const float* vrow = v_buf + (size_t)bs * N * D;
    float u = 0.f;
    for (int n = wv; n < N; n += 4)
        u += attn[(size_t)(b * N + n) * S + s] * vrow[n * D + d];
    __shared__ float part[4][64];
    part[wv][d] = u;
    __syncthreads();
    __shared__ float ul[64], hl[64];
    if (tid < 64) {
        ul[d] = part[0][d] + part[1][d] + part[2][d] + part[3][d];
        hl[d] = slots[bs * D + d];
    }
    __syncthreads();
    __shared__ float gx[192], gh[192];
    if (tid < 192) {
        float ax = gru_b[tid], ah = gru_b[192 + tid];
        #pragma unroll 8
        for (int i = 0; i < 64; ++i) {
            ax += ul[i] * gru_k[i * 192 + tid];
            ah += hl[i] * gru_rk[i * 192 + tid];
        }
        gx[tid] = ax; gh[tid] = ah;
    }
    __syncthreads();
    __shared__ float xl[64], snl[64];
    if (tid < 64) {
        float z = 1.f / (1.f + expf(-(gx[d] + gh[d])));
        float r = 1.f / (1.f + expf(-(gx[64 + d] + gh[64 + d])));
        float hc = tanhf(gx[128 + d] + r * gh[128 + d]);
        float sn = z * hl[d] + (1.f - z) * hc;
        snl[d] = sn;
        float sum = sn;
        #pragma unroll
        for (int off = 32; off > 0; off >>= 1) sum += __shfl_xor(sum, off);
        float mm = sum * (1.0f / 64.0f);
        float dx = sn - mm;
        float vs = dx * dx;
        #pragma unroll
        for (int off = 32; off > 0; off >>= 1) vs += __shfl_xor(vs, off);
        float var = vs * (1.0f / 64.0f);
        xl[d] = dx * rsqrtf(var + LN_EPS) * nm_g[d] + nm_b[d];
    }
    __syncthreads();
    __shared__ float hb[128];
    if (tid < 128) {
        int j = tid;
        float h1 = mlp_b1[j];
        #pragma unroll 8
        for (int i = 0; i < 64; ++i) h1 += xl[i] * mlp_w1[i * 128 + j];
        hb[j] = fmaxf(h1, 0.f);
    }
    __syncthreads();
    __shared__ float xq[64], qs[64];
    if (tid < 64) {
        float o = mlp_b2[d];
        #pragma unroll 8
        for (int j = 0; j < 128; ++j) o += hb[j] * mlp_w2[j * D + d];
        float res = snl[d] + o;
        slots[bs * D + d] = res;
        out_slots[bs * D + d] = res;
        // LN(ns) for next-iteration q
        float sum = res;
        #pragma unroll
        for (int off = 32; off > 0; off >>= 1) sum += __shfl_xor(sum, off);
        float mm = sum * (1.0f / 64.0f);
        float dx = res - mm;
        float vs = dx * dx;
        #pragma unroll
        for (int off = 32; off > 0; off >>= 1) vs += __shfl_xor(vs, off);
        float var = vs * (1.0f / 64.0f);
        xq[d] = dx * rsqrtf(var + LN_EPS) * ns_g[d] + ns_b[d];
    }
    __syncthreads();
    if (tid < 64) {
        float acc = pq_b[d];
        #pragma unroll 8
        for (int i = 0; i < 64; ++i) acc += xq[i] * pq_w[i * D + d];
        qs[d] = acc * 0.125f;
    }
    __syncthreads();
    if (tid < 128) {
        float sacc = 0.f;
        #pragma unroll 8
        for (int dd = 0; dd < 64; ++dd) sacc += mi_w2[tid * 64 + dd] * qs[dd];
        w2q[bs * 128 + tid] = sacc;
    }
    if (tid < 64) {
        float v = mi_b2[d] * qs[d];
        #pragma unroll
        for (int off = 32; off > 0; off >>= 1) v += __shfl_xor(v, off);
        if (d == 0) b2q[bs] = v;
    }
}

extern "C" void kernel_launch(void* const* d_in, const int* in_sizes, int n_in,
                              void* d_out, int out_size, void* d_ws, size_t ws_size,
                              hipStream_t stream) {
    const float* inputs  = (const float*)d_in[0];
    const float* s_p0    = (const float*)d_in[1];
    const float* s_s0    = (const float*)d_in[2];
    const float* slots_mu= (const float*)d_in[3];
    const float* es_w1   = (const float*)d_in[4];
    const float* es_b1   = (const float*)d_in[5];
    const float* es_w2   = (const float*)d_in[6];
    const float* es_b2   = (const float*)d_in[7];
    const float* er_w    = (const float*)d_in[8];
    const float* er_b    = (const float*)d_in[9];
    const float* pk_w    = (const float*)d_in[10];
    const float* pk_b    = (const float*)d_in[11];
    const float* pv_w    = (const float*)d_in[12];
    const float* pv_b    = (const float*)d_in[13];
    const float* pq_w    = (const float*)d_in[14];
    const float* pq_b    = (const float*)d_in[15];
    const float* mi_w1   = (const float*)d_in[16];
    const float* mi_b1   = (const float*)d_in[17];
    const float* mi_w2   = (const float*)d_in[18];
    const float* mi_b2   = (const float*)d_in[19];
    const float* ns_g    = (const float*)d_in[20];
    const float* ns_b    = (const float*)d_in[21];
    const float* nm_g    = (const float*)d_in[22];
    const float* nm_b    = (const float*)d_in[23];
    const float* gru_k   = (const float*)d_in[24];
    const float* gru_rk  = (const float*)d_in[25];
    const float* gru_b   = (const float*)d_in[26];
    const float* mlp_w1  = (const float*)d_in[27];
    const float* mlp_b1  = (const float*)d_in[28];
    const float* mlp_w2  = (const float*)d_in[29];
    const float* mlp_b2  = (const float*)d_in[30];

    float* ws    = (float*)d_ws;
    float* pos   = ws;                       // 131072
    float* GkT   = pos   + 131072;           // 1048576
    float* Gv    = GkT   + 1048576;          // 1048576
    float* vb    = Gv    + 1048576;          // 5767168
    float* lgts  = vb    + 5767168;          // 90112
    float* slots = lgts  + 90112;            // 22528
    float* sp    = slots + 22528;            // 704
    float* ssg   = sp    + 704;              // 704
    float* w2qb  = ssg   + 704;              // 45056
    float* b2qb  = w2qb  + 45056;            // 352
    float* ewp   = b2qb  + 352;              // 512
    u16*   wkT   = (u16*)(ewp + 512);        // 65536 u16
    u16*   wvT   = wkT + 65536;              // 65536 u16
    u16*   w2t   = wvT + 65536;              // 8192 u16

    float* out      = (float*)d_out;
    float* out_sp   = out + B * S * D;            // 704
    float* out_ss   = out_sp + B * S * 2;         // 704
    float* attn_out = out_ss + B * S * 2;         // 90112

    pos_kernel<<<256, 128, 0, stream>>>(es_w1, es_b1, es_w2, es_b2, pos);
    wprep_kernel<<<546, 256, 0, stream>>>(mi_w1, mi_b1, mi_w2, pk_w, pk_b, pv_w, pv_b,
                                          er_w, er_b, wkT, wvT, w2t, ewp);
    init_kernel<<<88, 256, 0, stream>>>(slots_mu, s_p0, s_s0, slots, sp, ssg);
    xw1_kernel<<<256, 256, 0, stream>>>(inputs, pos, wkT, GkT, Gv);
    qw2q_kernel<<<352, 128, 0, stream>>>(slots, ns_g, ns_b, pq_w, pq_b,
                                         mi_w2, mi_b2, w2qb, b2qb);

    for (int ind = 0; ind < 4; ++ind) {
        klogits_kernel<<<704, 128, 0, stream>>>(GkT, sp, ssg, ewp, w2qb, b2qb, lgts);
        vff_kernel<<<704, 256, 0, stream>>>(Gv, sp, ssg, ewp, w2t, mi_b2, vb);
        attn_kernel<<<32, 256, 0, stream>>>(lgts, attn_out, sp, ssg, out_sp, out_ss);
        if (ind < 3)
            update_kernel<<<352, 256, 0, stream>>>(attn_out, vb, gru_k, gru_rk, gru_b,
                                                   nm_g, nm_b, mlp_w1, mlp_b1,
                                                   mlp_w2, mlp_b2, ns_g, ns_b,
                                                   pq_w, pq_b, mi_w2, mi_b2,
                                                   slots, out, w2qb, b2qb);
    }
}

// Round 5
// 220.797 us; speedup vs baseline: 6.4499x; 1.3563x over previous
//
#include <hip/hip_runtime.h>
#include <cmath>

#define B 32
#define S 11
#define R 16
#define D 64
#define C 512
#define N 256   // R*R
#define LN_EPS 1e-3f

typedef unsigned short u16;
typedef unsigned int   u32;

using bf16x8 = __attribute__((ext_vector_type(8))) short;
using f32x4  = __attribute__((ext_vector_type(4))) float;

__device__ __forceinline__ float grid_coord(int i) {
    return -1.0f + (2.0f / 15.0f) * (float)i;
}

__device__ __forceinline__ u16 f2bf(float x) {
    union { float f; u32 u; } c; c.f = x;
    u32 r = c.u + 0x7fffu + ((c.u >> 16) & 1u);   // RNE
    return (u16)(r >> 16);
}

// ---------------- K0: positional embedding pos[n, c] (once) ----------------
__global__ __launch_bounds__(128) void pos_kernel(
    const float* __restrict__ es_w1, const float* __restrict__ es_b1,
    const float* __restrict__ es_w2, const float* __restrict__ es_b2,
    float* __restrict__ pos) {
    int n = blockIdx.x;       // 0..255
    int j = threadIdx.x;      // 0..127
    float g0 = grid_coord(n >> 4), g1 = grid_coord(n & 15);
    __shared__ float h[128];
    float hj = es_b1[j] + g0 * es_w1[j] + g1 * es_w1[128 + j];
    h[j] = fmaxf(hj, 0.0f);
    __syncthreads();
    for (int c0 = 0; c0 < C; c0 += 128) {
        int c = c0 + j;
        float acc = es_b2[c];
        #pragma unroll 16
        for (int jj = 0; jj < 128; ++jj) acc += h[jj] * es_w2[jj * C + c];
        pos[n * C + c] = acc;
    }
}

// ---------------- K_init ----------------------------------------------------
__global__ void init_kernel(
    const float* __restrict__ slots_mu, const float* __restrict__ s_p0,
    const float* __restrict__ s_s0,
    float* __restrict__ slots, float* __restrict__ s_p, float* __restrict__ s_s) {
    int idx = blockIdx.x * blockDim.x + threadIdx.x;
    if (idx < B * S * D) slots[idx] = slots_mu[idx % (S * D)];
    if (idx < B * S * 2) { s_p[idx] = s_p0[idx]; s_s[idx] = s_s0[idx]; }
}

// ---------------- K_wprep: all weight prep (once) ---------------------------
__global__ __launch_bounds__(256) void wprep_kernel(
    const float* __restrict__ mi_w1, const float* __restrict__ mi_b1,
    const float* __restrict__ mi_w2,
    const float* __restrict__ pk_w, const float* __restrict__ pk_b,
    const float* __restrict__ pv_w, const float* __restrict__ pv_b,
    const float* __restrict__ er_w, const float* __restrict__ er_b,
    u16* __restrict__ wkT, u16* __restrict__ wvT, u16* __restrict__ w2t,
    float* __restrict__ ewp) {
    int idx = blockIdx.x * 256 + threadIdx.x;
    if (idx < 131072) {
        int mat = idx >> 16;           // 0=k, 1=v
        int i = idx & 65535;
        int c = i >> 7, j = i & 127;
        const float* pw = mat ? pv_w : pk_w;
        float acc = 0.f;
        #pragma unroll 8
        for (int k = 0; k < 64; ++k) acc += pw[c * 64 + k] * mi_w1[k * 128 + j];
        u16* dst = mat ? wvT : wkT;
        dst[j * 512 + c] = f2bf(acc);
    } else if (idx < 139264) {
        int i = idx - 131072;          // 0..8191
        int dd = i >> 7, j = i & 127;
        w2t[i] = f2bf(mi_w2[j * 64 + dd]);
    } else if (idx < 139776) {
        int i = idx - 139264;          // 0..511
        int t = i >> 7, j = i & 127;
        float acc = 0.f;
        if (t == 0) {
            for (int k = 0; k < 64; ++k) acc += er_w[k] * mi_w1[k * 128 + j];
        } else if (t == 1) {
            for (int k = 0; k < 64; ++k) acc += er_w[64 + k] * mi_w1[k * 128 + j];
        } else if (t == 2) {
            for (int k = 0; k < 64; ++k) acc += (pk_b[k] + er_b[k]) * mi_w1[k * 128 + j];
            acc += mi_b1[j];
        } else {
            for (int k = 0; k < 64; ++k) acc += (pv_b[k] + er_b[k]) * mi_w1[k * 128 + j];
            acc += mi_b1[j];
        }
        ewp[i] = acc;
    }
}

// ---------------- K1: G = (inputs+pos) @ Wk1 / Wv1 via MFMA (once) ----------
// 512 blocks x 16 rows; each block computes BOTH GkT[b][j][n] and Gv[b][n][j].
__global__ __launch_bounds__(256) void xw1_kernel(
    const float* __restrict__ inputs, const float* __restrict__ pos,
    const u16* __restrict__ wkT,      // wvT at +65536
    float* __restrict__ GkT, float* __restrict__ Gv) {
    int tile = blockIdx.x;            // 0..511
    int row0 = tile * 16;
    int t = threadIdx.x;
    __shared__ u16 Xs[16 * 512];      // 16 KB, XOR-swizzled

    // stage: fully coalesced flat float4 walk (2048 float4 = 16 rows x 512 c)
    const float4* in4 = (const float4*)(inputs + (size_t)row0 * C);
    #pragma unroll
    for (int it = 0; it < 8; ++it) {
        int f = it * 256 + t;         // float4 index
        int lr = f >> 7;              // local row
        int c = (f & 127) * 4;
        float4 a = in4[f];
        float4 p = *(const float4*)(pos + (size_t)((row0 + lr) & (N - 1)) * C + c);
        u32 lo = (u32)f2bf(a.x + p.x) | ((u32)f2bf(a.y + p.y) << 16);
        u32 hi = (u32)f2bf(a.z + p.z) | ((u32)f2bf(a.w + p.w) << 16);
        int cs = c ^ ((lr & 7) << 3);
        *(uint2*)&Xs[lr * 512 + cs] = make_uint2(lo, hi);
    }
    __syncthreads();

    int w = t >> 6, l = t & 63;
    int l16 = l & 15, lq = l >> 4;
    int wc = w * 32;                  // this wave's 32 output cols
    int b = row0 >> 8, nb = row0 & (N - 1);

    f32x4 acc[2][2];                  // [mat][nt]
    #pragma unroll
    for (int m = 0; m < 2; ++m)
        #pragma unroll
        for (int nt = 0; nt < 2; ++nt) acc[m][nt] = (f32x4){0.f, 0.f, 0.f, 0.f};

    for (int kt = 0; kt < 16; ++kt) {
        int k0 = kt * 32 + lq * 8;
        int ks = k0 ^ ((l16 & 7) << 3);
        bf16x8 xf = *(const bf16x8*)&Xs[l16 * 512 + ks];
        #pragma unroll
        for (int m = 0; m < 2; ++m) {
            const u16* Wm = wkT + (size_t)m * 65536;
            #pragma unroll
            for (int nt = 0; nt < 2; ++nt) {
                bf16x8 wf = *(const bf16x8*)(Wm + (size_t)(wc + nt * 16 + l16) * 512 + k0);
                if (m == 0)
                    acc[m][nt] = __builtin_amdgcn_mfma_f32_16x16x32_bf16(wf, xf, acc[m][nt], 0, 0, 0);
                else
                    acc[m][nt] = __builtin_amdgcn_mfma_f32_16x16x32_bf16(xf, wf, acc[m][nt], 0, 0, 0);
            }
        }
    }
    #pragma unroll
    for (int nt = 0; nt < 2; ++nt) {
        #pragma unroll
        for (int r = 0; r < 4; ++r) {
            int j = wc + nt * 16 + lq * 4 + r;
            GkT[(size_t)b * 32768 + (size_t)j * 256 + nb + l16] = acc[0][nt][r];
            int n2 = nb + lq * 4 + r;
            Gv[((size_t)b * 256 + n2) * 128 + wc + nt * 16 + l16] = acc[1][nt][r];
        }
    }
}

// ---------------- K2: initial q -> w2q, b2q (once) --------------------------
__global__ __launch_bounds__(128) void qw2q_kernel(
    const float* __restrict__ slots,
    const float* __restrict__ ns_g, const float* __restrict__ ns_b,
    const float* __restrict__ pq_w, const float* __restrict__ pq_b,
    const float* __restrict__ mi_w2, const float* __restrict__ mi_b2,
    float* __restrict__ w2q, float* __restrict__ b2q) {
    int bs = blockIdx.x;
    int t = threadIdx.x;
    __shared__ float xlds[64], qs[64];
    if (t < 64) {
        float x = slots[bs * D + t];
        float sum = x;
        #pragma unroll
        for (int off = 32; off > 0; off >>= 1) sum += __shfl_xor(sum, off);
        float m = sum * (1.0f / 64.0f);
        float dx = x - m;
        float vs = dx * dx;
        #pragma unroll
        for (int off = 32; off > 0; off >>= 1) vs += __shfl_xor(vs, off);
        float var = vs * (1.0f / 64.0f);
        xlds[t] = dx * rsqrtf(var + LN_EPS) * ns_g[t] + ns_b[t];
    }
    __syncthreads();
    if (t < 64) {
        float acc = pq_b[t];
        #pragma unroll 8
        for (int i = 0; i < 64; ++i) acc += xlds[i] * pq_w[i * D + t];
        qs[t] = acc * 0.125f;
    }
    __syncthreads();
    {
        float s = 0.f;
        #pragma unroll 8
        for (int dd = 0; dd < 64; ++dd) s += mi_w2[t * 64 + dd] * qs[dd];
        w2q[bs * 128 + t] = s;
    }
    if (t < 64) {
        float v = mi_b2[t] * qs[t];
        #pragma unroll
        for (int off = 32; off > 0; off >>= 1) v += __shfl_xor(v, off);
        if (t == 0) b2q[bs] = v;
    }
}

// ============ K3: merged k-logits + v-FF per (bs, half) =====================
__global__ __launch_bounds__(256) void kv_kernel(
    const float* __restrict__ GkT, const float* __restrict__ Gv,
    const float* __restrict__ s_p, const float* __restrict__ s_s,
    const float* __restrict__ ewp,
    const float* __restrict__ w2q, const float* __restrict__ b2q,
    const u16* __restrict__ w2t, const float* __restrict__ mi_b2,
    float* __restrict__ logits, float* __restrict__ v_buf) {
    int orig = blockIdx.x;                       // 704 = 8*88
    int blk = (orig & 7) * 88 + (orig >> 3);     // XCD-chunked swizzle
    int half = blk & 1;
    int bs = blk >> 1;
    int b = bs / S, s = bs - b * S;
    int t = threadIdx.x;

    __shared__ u16 Hs[128 * 128];
    __shared__ float e0s[128], e1s[128], bbk[128], bbv[128], wqs[128], lgpart[128];
    if (t < 128) {
        e0s[t] = ewp[t]; e1s[t] = ewp[128 + t];
        bbk[t] = ewp[256 + t]; bbv[t] = ewp[384 + t];
        wqs[t] = w2q[bs * 128 + t];
    }
    __syncthreads();

    float p0 = s_p[bs * 2 + 0], p1 = s_p[bs * 2 + 1];
    float ss0 = s_s[bs * 2 + 0], ss1 = s_s[bs * 2 + 1];

    // ---- Phase A: k-logits (2 threads per n, j split 64+64) ----
    {
        int n_loc = t & 127, jh = t >> 7;
        int n = half * 128 + n_loc;
        float g0 = grid_coord(n >> 4), g1 = grid_coord(n & 15);
        float r0 = (g0 - p0) / ss0, r1 = (g1 - p1) / ss1;
        const float* Gb = GkT + (size_t)b * 32768 + n;
        float acc = 0.f;
        int j0 = jh * 64;
        #pragma unroll 8
        for (int j = j0; j < j0 + 64; ++j) {
            float h = Gb[(size_t)j * 256] + r0 * e0s[j] + r1 * e1s[j] + bbk[j];
            acc += fmaxf(h, 0.f) * wqs[j];
        }
        if (jh) lgpart[n_loc] = acc;
        __syncthreads();
        if (!jh)
            logits[(size_t)(b * N + n) * S + s] = acc + lgpart[n_loc] + b2q[bs];
    }

    // ---- Phase B: v-FF layer1 (rank-2) -> Hs -> layer2 MFMA ----
    {
        int row = t >> 1;
        int jhf = (t & 1) * 64;
        int n = half * 128 + row;
        float g0 = grid_coord(n >> 4), g1 = grid_coord(n & 15);
        float r0 = (g0 - p0) / ss0, r1 = (g1 - p1) / ss1;
        const float* Gr = Gv + ((size_t)b * 256 + n) * 128 + jhf;
        #pragma unroll
        for (int g = 0; g < 16; ++g) {
            float4 gv = *(const float4*)(Gr + g * 4);
            int j0 = jhf + g * 4;
            float h0 = fmaxf(gv.x + r0 * e0s[j0 + 0] + r1 * e1s[j0 + 0] + bbv[j0 + 0], 0.f);
            float h1 = fmaxf(gv.y + r0 * e0s[j0 + 1] + r1 * e1s[j0 + 1] + bbv[j0 + 1], 0.f);
            float h2 = fmaxf(gv.z + r0 * e0s[j0 + 2] + r1 * e1s[j0 + 2] + bbv[j0 + 2], 0.f);
            float h3 = fmaxf(gv.w + r0 * e0s[j0 + 3] + r1 * e1s[j0 + 3] + bbv[j0 + 3], 0.f);
            u32 lo = (u32)f2bf(h0) | ((u32)f2bf(h1) << 16);
            u32 hi = (u32)f2bf(h2) | ((u32)f2bf(h3) << 16);
            int js = j0 ^ ((row & 15) << 3);
            *(uint2*)&Hs[row * 128 + js] = make_uint2(lo, hi);
        }
    }
    __syncthreads();

    int w = t >> 6;
    int l = t & 63;
    int l16 = l & 15, lq = l >> 4;

    f32x4 acc2[2][4];
    #pragma unroll
    for (int mt = 0; mt < 2; ++mt)
        #pragma unroll
        for (int nt = 0; nt < 4; ++nt)
            acc2[mt][nt] = (f32x4){0.f, 0.f, 0.f, 0.f};

    #pragma unroll
    for (int kt = 0; kt < 4; ++kt) {
        bf16x8 af[2], bw[4];
        #pragma unroll
        for (int mt = 0; mt < 2; ++mt) {
            int row = w * 32 + mt * 16 + l16;
            int js = (kt * 32 + lq * 8) ^ ((row & 15) << 3);
            af[mt] = *(const bf16x8*)&Hs[row * 128 + js];
        }
        #pragma unroll
        for (int nt = 0; nt < 4; ++nt) {
            int dd = nt * 16 + l16;
            bw[nt] = *(const bf16x8*)(w2t + dd * 128 + kt * 32 + lq * 8);
        }
        #pragma unroll
        for (int mt = 0; mt < 2; ++mt)
            #pragma unroll
            for (int nt = 0; nt < 4; ++nt)
                acc2[mt][nt] = __builtin_amdgcn_mfma_f32_16x16x32_bf16(af[mt], bw[nt], acc2[mt][nt], 0, 0, 0);
    }

    #pragma unroll
    for (int nt = 0; nt < 4; ++nt) {
        float b2v = mi_b2[nt * 16 + l16];
        #pragma unroll
        for (int mt = 0; mt < 2; ++mt) {
            #pragma unroll
            for (int r = 0; r < 4; ++r) {
                int n = half * 128 + w * 32 + mt * 16 + lq * 4 + r;
                v_buf[((size_t)bs * N + n) * D + nt * 16 + l16] = acc2[mt][nt][r] + b2v;
            }
        }
    }
}

// ============ K4: fused softmax/calcSP/updates/GRU/MLP/next-q per (b,s) =====
__global__ __launch_bounds__(256) void update_kernel(
    const float* __restrict__ logits, const float* __restrict__ v_buf,
    const float* __restrict__ gru_k, const float* __restrict__ gru_rk,
    const float* __restrict__ gru_b,
    const float* __restrict__ nm_g, const float* __restrict__ nm_b,
    const float* __restrict__ mlp_w1, const float* __restrict__ mlp_b1,
    const float* __restrict__ mlp_w2, const float* __restrict__ mlp_b2,
    const float* __restrict__ ns_g, const float* __restrict__ ns_b,
    const float* __restrict__ pq_w, const float* __restrict__ pq_b,
    const float* __restrict__ mi_w2, const float* __restrict__ mi_b2,
    float* __restrict__ slots, float* __restrict__ out_slots,
    float* __restrict__ s_p, float* __restrict__ s_s,
    float* __restrict__ w2q, float* __restrict__ b2q) {
    int orig = blockIdx.x;                    // 352 = 8*44
    int bs = (orig & 7) * 44 + (orig >> 3);
    int b = bs / S, s = bs - b * S;
    int t = threadIdx.x;
    int wv = t >> 6, l = t & 63, d = l;

    // --- softmax over slots for n = t; keep own-slot value ---
    const float* lr = logits + (size_t)(b * N + t) * S;
    float m = -1e30f;
    float lg[S];
    #pragma unroll
    for (int ss = 0; ss < S; ++ss) { lg[ss] = lr[ss]; m = fmaxf(m, lg[ss]); }
    float sum = 0.f, e_own = 0.f;
    #pragma unroll
    for (int ss = 0; ss < S; ++ss) {
        float e = expf(lg[ss] - m);
        sum += e;
        if (ss == s) e_own = e;
    }
    float a_n = e_own / sum + 1e-8f;
    float g0 = grid_coord(t >> 4), g1 = grid_coord(t & 15);

    __shared__ float red[3][4];
    __shared__ float a_lds[N];
    float sa = a_n, s0 = a_n * g0, s1 = a_n * g1;
    #pragma unroll
    for (int off = 32; off > 0; off >>= 1) {
        sa += __shfl_xor(sa, off);
        s0 += __shfl_xor(s0, off);
        s1 += __shfl_xor(s1, off);
    }
    if (l == 0) { red[0][wv] = sa; red[1][wv] = s0; red[2][wv] = s1; }
    __syncthreads();
    float SA = red[0][0] + red[0][1] + red[0][2] + red[0][3];
    float wp0 = (red[1][0] + red[1][1] + red[1][2] + red[1][3]) / SA;
    float wp1 = (red[2][0] + red[2][1] + red[2][2] + red[2][3]) / SA;
    float inv_sa = 1.0f / SA;
    float av = a_n * inv_sa + 1e-11f;
    float d0 = g0 - wp0, d1 = g1 - wp1;
    float t0 = d0 * d0 * av, t1 = d1 * d1 * av;
    #pragma unroll
    for (int off = 32; off > 0; off >>= 1) {
        t0 += __shfl_xor(t0, off);
        t1 += __shfl_xor(t1, off);
    }
    __syncthreads();
    if (l == 0) { red[0][wv] = t0; red[1][wv] = t1; }
    a_lds[t] = a_n * inv_sa;
    __syncthreads();
    if (t == 0) {
        float T0 = red[0][0] + red[0][1] + red[0][2] + red[0][3];
        float T1 = red[1][0] + red[1][1] + red[1][2] + red[1][3];
        s_p[bs * 2 + 0] = wp0;
        s_p[bs * 2 + 1] = wp1;
        s_s[bs * 2 + 0] = fminf(fmaxf(sqrtf(T0), 0.001f), 5.0f);
        s_s[bs * 2 + 1] = fminf(fmaxf(sqrtf(T1), 0.001f), 5.0f);
    }

    // --- updates = sum_n attn_renorm[n] * v[n][d] ---
    const float* vrow = v_buf + (size_t)bs * N * D;
    float u = 0.f;
    for (int n = wv; n < N; n += 4)
        u += a_lds[n] * vrow[n * D + d];
    __shared__ float part[4][64];
    part[wv][d] = u;
    __syncthreads();
    __shared__ float ul[64], hl[64];
    if (t < 64) {
        ul[d] = part[0][d] + part[1][d] + part[2][d] + part[3][d];
        hl[d] = slots[bs * D + d];
    }
    __syncthreads();
    __shared__ float gx[192], gh[192];
    if (t < 192) {
        float ax = gru_b[t], ah = gru_b[192 + t];
        #pragma unroll 8
        for (int i = 0; i < 64; ++i) {
            ax += ul[i] * gru_k[i * 192 + t];
            ah += hl[i] * gru_rk[i * 192 + t];
        }
        gx[t] = ax; gh[t] = ah;
    }
    __syncthreads();
    __shared__ float xl[64], snl[64];
    if (t < 64) {
        float z = 1.f / (1.f + expf(-(gx[d] + gh[d])));
        float r = 1.f / (1.f + expf(-(gx[64 + d] + gh[64 + d])));
        float hc = tanhf(gx[128 + d] + r * gh[128 + d]);
        float sn = z * hl[d] + (1.f - z) * hc;
        snl[d] = sn;
        float sm = sn;
        #pragma unroll
        for (int off = 32; off > 0; off >>= 1) sm += __shfl_xor(sm, off);
        float mm = sm * (1.0f / 64.0f);
        float dx = sn - mm;
        float vs = dx * dx;
        #pragma unroll
        for (int off = 32; off > 0; off >>= 1) vs += __shfl_xor(vs, off);
        float var = vs * (1.0f / 64.0f);
        xl[d] = dx * rsqrtf(var + LN_EPS) * nm_g[d] + nm_b[d];
    }
    __syncthreads();
    __shared__ float hb[128];
    if (t < 128) {
        float h1 = mlp_b1[t];
        #pragma unroll 8
        for (int i = 0; i < 64; ++i) h1 += xl[i] * mlp_w1[i * 128 + t];
        hb[t] = fmaxf(h1, 0.f);
    }
    __syncthreads();
    __shared__ float xq[64], qs[64];
    if (t < 64) {
        float o = mlp_b2[d];
        #pragma unroll 8
        for (int j = 0; j < 128; ++j) o += hb[j] * mlp_w2[j * D + d];
        float res = snl[d] + o;
        slots[bs * D + d] = res;
        out_slots[bs * D + d] = res;
        float sm = res;
        #pragma unroll
        for (int off = 32; off > 0; off >>= 1) sm += __shfl_xor(sm, off);
        float mm = sm * (1.0f / 64.0f);
        float dx = res - mm;
        float vs = dx * dx;
        #pragma unroll
        for (int off = 32; off > 0; off >>= 1) vs += __shfl_xor(vs, off);
        float var = vs * (1.0f / 64.0f);
        xq[d] = dx * rsqrtf(var + LN_EPS) * ns_g[d] + ns_b[d];
    }
    __syncthreads();
    if (t < 64) {
        float acc = pq_b[d];
        #pragma unroll 8
        for (int i = 0; i < 64; ++i) acc += xq[i] * pq_w[i * D + d];
        qs[d] = acc * 0.125f;
    }
    __syncthreads();
    if (t < 128) {
        float sacc = 0.f;
        #pragma unroll 8
        for (int dd = 0; dd < 64; ++dd) sacc += mi_w2[t * 64 + dd] * qs[dd];
        w2q[bs * 128 + t] = sacc;
    }
    if (t < 64) {
        float v = mi_b2[d] * qs[d];
        #pragma unroll
        for (int off = 32; off > 0; off >>= 1) v += __shfl_xor(v, off);
        if (d == 0) b2q[bs] = v;
    }
}

// ============ K5: final iteration — attn output + s_p/s_s outputs ===========
__global__ __launch_bounds__(256) void final_kernel(
    const float* __restrict__ logits,
    float* __restrict__ attn_out, float* __restrict__ osp, float* __restrict__ oss) {
    int orig = blockIdx.x;
    int bs = (orig & 7) * 44 + (orig >> 3);
    int b = bs / S, s = bs - b * S;
    int t = threadIdx.x;
    int wv = t >> 6, l = t & 63;

    const float* lr = logits + (size_t)(b * N + t) * S;
    float m = -1e30f;
    float lg[S];
    #pragma unroll
    for (int ss = 0; ss < S; ++ss) { lg[ss] = lr[ss]; m = fmaxf(m, lg[ss]); }
    float sum = 0.f, e_own = 0.f;
    #pragma unroll
    for (int ss = 0; ss < S; ++ss) {
        float e = expf(lg[ss] - m);
        sum += e;
        if (ss == s) e_own = e;
    }
    float a_n = e_own / sum + 1e-8f;
    float g0 = grid_coord(t >> 4), g1 = grid_coord(t & 15);

    __shared__ float red[3][4];
    float sa = a_n, s0 = a_n * g0, s1 = a_n * g1;
    #pragma unroll
    for (int off = 32; off > 0; off >>= 1) {
        sa += __shfl_xor(sa, off);
        s0 += __shfl_xor(s0, off);
        s1 += __shfl_xor(s1, off);
    }
    if (l == 0) { red[0][wv] = sa; red[1][wv] = s0; red[2][wv] = s1; }
    __syncthreads();
    float SA = red[0][0] + red[0][1] + red[0][2] + red[0][3];
    float wp0 = (red[1][0] + red[1][1] + red[1][2] + red[1][3]) / SA;
    float wp1 = (red[2][0] + red[2][1] + red[2][2] + red[2][3]) / SA;
    float inv_sa = 1.0f / SA;
    float av = a_n * inv_sa + 1e-11f;
    float d0 = g0 - wp0, d1 = g1 - wp1;
    float t0 = d0 * d0 * av, t1 = d1 * d1 * av;
    #pragma unroll
    for (int off = 32; off > 0; off >>= 1) {
        t0 += __shfl_xor(t0, off);
        t1 += __shfl_xor(t1, off);
    }
    __syncthreads();
    if (l == 0) { red[0][wv] = t0; red[1][wv] = t1; }
    __syncthreads();
    if (t == 0) {
        float T0 = red[0][0] + red[0][1] + red[0][2] + red[0][3];
        float T1 = red[1][0] + red[1][1] + red[1][2] + red[1][3];
        osp[bs * 2 + 0] = wp0;
        osp[bs * 2 + 1] = wp1;
        oss[bs * 2 + 0] = fminf(fmaxf(sqrtf(T0), 0.001f), 5.0f);
        oss[bs * 2 + 1] = fminf(fmaxf(sqrtf(T1), 0.001f), 5.0f);
    }
    attn_out[(size_t)(b * N + t) * S + s] = a_n * inv_sa;
}

extern "C" void kernel_launch(void* const* d_in, const int* in_sizes, int n_in,
                              void* d_out, int out_size, void* d_ws, size_t ws_size,
                              hipStream_t stream) {
    const float* inputs  = (const float*)d_in[0];
    const float* s_p0    = (const float*)d_in[1];
    const float* s_s0    = (const float*)d_in[2];
    const float* slots_mu= (const float*)d_in[3];
    const float* es_w1   = (const float*)d_in[4];
    const float* es_b1   = (const float*)d_in[5];
    const float* es_w2   = (const float*)d_in[6];
    const float* es_b2   = (const float*)d_in[7];
    const float* er_w    = (const float*)d_in[8];
    const float* er_b    = (const float*)d_in[9];
    const float* pk_w    = (const float*)d_in[10];
    const float* pk_b    = (const float*)d_in[11];
    const float* pv_w    = (const float*)d_in[12];
    const float* pv_b    = (const float*)d_in[13];
    const float* pq_w    = (const float*)d_in[14];
    const float* pq_b    = (const float*)d_in[15];
    const float* mi_w1   = (const float*)d_in[16];
    const float* mi_b1   = (const float*)d_in[17];
    const float* mi_w2   = (const float*)d_in[18];
    const float* mi_b2   = (const float*)d_in[19];
    const float* ns_g    = (const float*)d_in[20];
    const float* ns_b    = (const float*)d_in[21];
    const float* nm_g    = (const float*)d_in[22];
    const float* nm_b    = (const float*)d_in[23];
    const float* gru_k   = (const float*)d_in[24];
    const float* gru_rk  = (const float*)d_in[25];
    const float* gru_b   = (const float*)d_in[26];
    const float* mlp_w1  = (const float*)d_in[27];
    const float* mlp_b1  = (const float*)d_in[28];
    const float* mlp_w2  = (const float*)d_in[29];
    const float* mlp_b2  = (const float*)d_in[30];

    float* ws    = (float*)d_ws;
    float* pos   = ws;                       // 131072
    float* GkT   = pos   + 131072;           // 1048576
    float* Gv    = GkT   + 1048576;          // 1048576
    float* vb    = Gv    + 1048576;          // 5767168
    float* lgts  = vb    + 5767168;          // 90112
    float* slots = lgts  + 90112;            // 22528
    float* sp    = slots + 22528;            // 704
    float* ssg   = sp    + 704;              // 704
    float* w2qb  = ssg   + 704;              // 45056
    float* b2qb  = w2qb  + 45056;            // 352
    float* ewp   = b2qb  + 352;              // 512
    u16*   wkT   = (u16*)(ewp + 512);        // 65536 u16 (wvT follows at +65536)
    u16*   wvT   = wkT + 65536;              // 65536 u16
    u16*   w2t   = wvT + 65536;              // 8192 u16

    float* out      = (float*)d_out;
    float* out_sp   = out + B * S * D;            // 704
    float* out_ss   = out_sp + B * S * 2;         // 704
    float* attn_out = out_ss + B * S * 2;         // 90112

    pos_kernel<<<256, 128, 0, stream>>>(es_w1, es_b1, es_w2, es_b2, pos);
    wprep_kernel<<<546, 256, 0, stream>>>(mi_w1, mi_b1, mi_w2, pk_w, pk_b, pv_w, pv_b,
                                          er_w, er_b, wkT, wvT, w2t, ewp);
    init_kernel<<<88, 256, 0, stream>>>(slots_mu, s_p0, s_s0, slots, sp, ssg);
    xw1_kernel<<<512, 256, 0, stream>>>(inputs, pos, wkT, GkT, Gv);
    qw2q_kernel<<<352, 128, 0, stream>>>(slots, ns_g, ns_b, pq_w, pq_b,
                                         mi_w2, mi_b2, w2qb, b2qb);

    for (int ind = 0; ind < 4; ++ind) {
        kv_kernel<<<704, 256, 0, stream>>>(GkT, Gv, sp, ssg, ewp, w2qb, b2qb,
                                           w2t, mi_b2, lgts, vb);
        if (ind < 3)
            update_kernel<<<352, 256, 0, stream>>>(lgts, vb, gru_k, gru_rk, gru_b,
                                                   nm_g, nm_b, mlp_w1, mlp_b1,
                                                   mlp_w2, mlp_b2, ns_g, ns_b,
                                                   pq_w, pq_b, mi_w2, mi_b2,
                                                   slots, out, sp, ssg, w2qb, b2qb);
        else
            final_kernel<<<352, 256, 0, stream>>>(lgts, attn_out, out_sp, out_ss);
    }
}